// Round 5
// baseline (3982.925 us; speedup 1.0000x reference)
//
#include <hip/hip_runtime.h>
#include <hip/hip_bf16.h>
#include <stdint.h>

#define DDIM 256
#define BROWS 32          // dst rows per bucket
#define BCAP 768          // record capacity per bucket (mean 512, +11 sigma)

typedef short s8v __attribute__((ext_vector_type(8)));
typedef float f4v __attribute__((ext_vector_type(4)));

__device__ __forceinline__ float bf2f(unsigned u) { return __uint_as_float(u << 16); }
__device__ __forceinline__ unsigned short f2bf(float f) {
    __hip_bfloat16 h = __float2bfloat16(f);
    return *reinterpret_cast<unsigned short*>(&h);
}
__device__ __forceinline__ unsigned pack2(float a, float b) {
    return (unsigned)f2bf(a) | ((unsigned)f2bf(b) << 16);
}

// ---------------- fused W transpose + cast: T[n][k] = bf16(W[k][n]) ----------------
__global__ void transpose3_k(const float* __restrict__ W0, const float* __restrict__ W1,
                             const float* __restrict__ W2, __hip_bfloat16* __restrict__ T0,
                             __hip_bfloat16* __restrict__ T1, __hip_bfloat16* __restrict__ T2) {
    const float* W = (blockIdx.y == 0) ? W0 : (blockIdx.y == 1) ? W1 : W2;
    __hip_bfloat16* T = (blockIdx.y == 0) ? T0 : (blockIdx.y == 1) ? T1 : T2;
    T[blockIdx.x * DDIM + threadIdx.x] = __float2bfloat16(W[threadIdx.x * DDIM + blockIdx.x]);
}

// ---------------- bin: src-degree count + bucket-append packed records ----------------
// record = src | (dst&31)<<16 ; bucket = dst>>5. Frontier lines stay L2-hot -> coalesced.
__global__ void bin_k(const int* __restrict__ s0, const int* __restrict__ d0,
                      const int* __restrict__ s1, const int* __restrict__ d1,
                      const int* __restrict__ s2, const int* __restrict__ d2,
                      int* __restrict__ cs,            // 3 x n (deg_out per relation)
                      int* __restrict__ cur,           // 3 x nb cursors
                      unsigned* __restrict__ recs,     // 3 x nb x BCAP
                      int n, int nb, int E) {
    const int i = blockIdx.x * blockDim.x + threadIdx.x;
    if (i >= E) return;
    {
        const int s = s0[i], d = d0[i];
        atomicAdd(cs + s, 1);
        const int pos = atomicAdd(cur + (d >> 5), 1);
        if (pos < BCAP) recs[(size_t)(d >> 5) * BCAP + pos] = (unsigned)s | ((unsigned)(d & 31) << 16);
    }
    {
        const int s = s1[i], d = d1[i];
        atomicAdd(cs + n + s, 1);
        const int pos = atomicAdd(cur + nb + (d >> 5), 1);
        if (pos < BCAP) recs[((size_t)nb + (d >> 5)) * BCAP + pos] = (unsigned)s | ((unsigned)(d & 31) << 16);
    }
    {
        const int s = s2[i], d = d2[i];
        atomicAdd(cs + 2 * n + s, 1);
        const int pos = atomicAdd(cur + 2 * nb + (d >> 5), 1);
        if (pos < BCAP) recs[((size_t)2 * nb + (d >> 5)) * BCAP + pos] = (unsigned)s | ((unsigned)(d & 31) << 16);
    }
}

// ---------------- dual-output GEMM: Y0 = bf16(s0(X@W0)), Y1 = bf16(s1(X@W1)) ----------------
__global__ __launch_bounds__(256) void gemm2_k(
    const float* __restrict__ X,
    const __hip_bfloat16* __restrict__ Wt0, const __hip_bfloat16* __restrict__ Wt1,
    const int* __restrict__ deg0, const int* __restrict__ deg1,
    __hip_bfloat16* __restrict__ Y0, __hip_bfloat16* __restrict__ Y1, int M) {
    const int lane = threadIdx.x & 63, wid = threadIdx.x >> 6;
    const int c = lane & 15, kb = lane >> 4;
    const int rA = blockIdx.x * 128 + wid * 32 + c;
    const int rB = rA + 16;
    const bool vA = rA < M, vB = rB < M;
    const int rAc = vA ? rA : (M - 1), rBc = vB ? rB : (M - 1);

    s8v xfA[8], xfB[8];
    const float* xA = X + (size_t)rAc * DDIM;
    const float* xB = X + (size_t)rBc * DDIM;
    #pragma unroll
    for (int ks = 0; ks < 8; ++ks) {
        const int k0 = ks * 32 + kb * 8;
        const f4v a0 = *reinterpret_cast<const f4v*>(xA + k0);
        const f4v a1 = *reinterpret_cast<const f4v*>(xA + k0 + 4);
        const f4v b0 = *reinterpret_cast<const f4v*>(xB + k0);
        const f4v b1 = *reinterpret_cast<const f4v*>(xB + k0 + 4);
        union { s8v v; unsigned short u[8]; } fa, fb;
        #pragma unroll
        for (int j = 0; j < 4; ++j) {
            fa.u[j] = f2bf(a0[j]); fa.u[4 + j] = f2bf(a1[j]);
            fb.u[j] = f2bf(b0[j]); fb.u[4 + j] = f2bf(b1[j]);
        }
        xfA[ks] = fa.v; xfB[ks] = fb.v;
    }

    const int dA0 = deg0[rAc], dB0 = deg0[rBc], dA1 = deg1[rAc], dB1 = deg1[rBc];
    const float s0A = rsqrtf((float)(dA0 < 1 ? 1 : dA0));
    const float s0B = rsqrtf((float)(dB0 < 1 ? 1 : dB0));
    const float s1A = rsqrtf((float)(dA1 < 1 ? 1 : dA1));
    const float s1B = rsqrtf((float)(dB1 < 1 ? 1 : dB1));

    #pragma unroll 2
    for (int nt = 0; nt < 16; ++nt) {
        const __hip_bfloat16* w0p = Wt0 + (size_t)(nt * 16 + c) * DDIM + kb * 8;
        const __hip_bfloat16* w1p = Wt1 + (size_t)(nt * 16 + c) * DDIM + kb * 8;
        s8v wf0[8], wf1[8];
        #pragma unroll
        for (int ks = 0; ks < 8; ++ks) {
            wf0[ks] = *reinterpret_cast<const s8v*>(w0p + ks * 32);
            wf1[ks] = *reinterpret_cast<const s8v*>(w1p + ks * 32);
        }
        f4v a00 = (f4v){0.f,0.f,0.f,0.f}, a01 = a00, a10 = a00, a11 = a00;
        #pragma unroll
        for (int ks = 0; ks < 8; ++ks) {
            a00 = __builtin_amdgcn_mfma_f32_16x16x32_bf16(wf0[ks], xfA[ks], a00, 0, 0, 0);
            a10 = __builtin_amdgcn_mfma_f32_16x16x32_bf16(wf0[ks], xfB[ks], a10, 0, 0, 0);
            a01 = __builtin_amdgcn_mfma_f32_16x16x32_bf16(wf1[ks], xfA[ks], a01, 0, 0, 0);
            a11 = __builtin_amdgcn_mfma_f32_16x16x32_bf16(wf1[ks], xfB[ks], a11, 0, 0, 0);
        }
        const int col = nt * 16 + kb * 4;
        if (vA) {
            uint2 o0, o1;
            o0.x = pack2(a00[0] * s0A, a00[1] * s0A); o0.y = pack2(a00[2] * s0A, a00[3] * s0A);
            o1.x = pack2(a01[0] * s1A, a01[1] * s1A); o1.y = pack2(a01[2] * s1A, a01[3] * s1A);
            *reinterpret_cast<uint2*>(Y0 + (size_t)rA * DDIM + col) = o0;
            *reinterpret_cast<uint2*>(Y1 + (size_t)rA * DDIM + col) = o1;
        }
        if (vB) {
            uint2 o0, o1;
            o0.x = pack2(a10[0] * s0B, a10[1] * s0B); o0.y = pack2(a10[2] * s0B, a10[3] * s0B);
            o1.x = pack2(a11[0] * s1B, a11[1] * s1B); o1.y = pack2(a11[2] * s1B, a11[3] * s1B);
            *reinterpret_cast<uint2*>(Y0 + (size_t)rB * DDIM + col) = o0;
            *reinterpret_cast<uint2*>(Y1 + (size_t)rB * DDIM + col) = o1;
        }
    }
}

// ---------------- single-output GEMM ----------------
__global__ __launch_bounds__(256) void gemm1_k(
    const float* __restrict__ X, const __hip_bfloat16* __restrict__ Wt0,
    const int* __restrict__ deg0, __hip_bfloat16* __restrict__ Y0, int M) {
    const int lane = threadIdx.x & 63, wid = threadIdx.x >> 6;
    const int c = lane & 15, kb = lane >> 4;
    const int rA = blockIdx.x * 128 + wid * 32 + c;
    const int rB = rA + 16;
    const bool vA = rA < M, vB = rB < M;
    const int rAc = vA ? rA : (M - 1), rBc = vB ? rB : (M - 1);

    s8v xfA[8], xfB[8];
    const float* xA = X + (size_t)rAc * DDIM;
    const float* xB = X + (size_t)rBc * DDIM;
    #pragma unroll
    for (int ks = 0; ks < 8; ++ks) {
        const int k0 = ks * 32 + kb * 8;
        const f4v a0 = *reinterpret_cast<const f4v*>(xA + k0);
        const f4v a1 = *reinterpret_cast<const f4v*>(xA + k0 + 4);
        const f4v b0 = *reinterpret_cast<const f4v*>(xB + k0);
        const f4v b1 = *reinterpret_cast<const f4v*>(xB + k0 + 4);
        union { s8v v; unsigned short u[8]; } fa, fb;
        #pragma unroll
        for (int j = 0; j < 4; ++j) {
            fa.u[j] = f2bf(a0[j]); fa.u[4 + j] = f2bf(a1[j]);
            fb.u[j] = f2bf(b0[j]); fb.u[4 + j] = f2bf(b1[j]);
        }
        xfA[ks] = fa.v; xfB[ks] = fb.v;
    }
    const int dA0 = deg0[rAc], dB0 = deg0[rBc];
    const float s0A = rsqrtf((float)(dA0 < 1 ? 1 : dA0));
    const float s0B = rsqrtf((float)(dB0 < 1 ? 1 : dB0));

    #pragma unroll 2
    for (int nt = 0; nt < 16; ++nt) {
        const __hip_bfloat16* w0p = Wt0 + (size_t)(nt * 16 + c) * DDIM + kb * 8;
        s8v wf0[8];
        #pragma unroll
        for (int ks = 0; ks < 8; ++ks) wf0[ks] = *reinterpret_cast<const s8v*>(w0p + ks * 32);
        f4v a00 = (f4v){0.f,0.f,0.f,0.f}, a10 = a00;
        #pragma unroll
        for (int ks = 0; ks < 8; ++ks) {
            a00 = __builtin_amdgcn_mfma_f32_16x16x32_bf16(wf0[ks], xfA[ks], a00, 0, 0, 0);
            a10 = __builtin_amdgcn_mfma_f32_16x16x32_bf16(wf0[ks], xfB[ks], a10, 0, 0, 0);
        }
        const int col = nt * 16 + kb * 4;
        if (vA) {
            uint2 o;
            o.x = pack2(a00[0] * s0A, a00[1] * s0A); o.y = pack2(a00[2] * s0A, a00[3] * s0A);
            *reinterpret_cast<uint2*>(Y0 + (size_t)rA * DDIM + col) = o;
        }
        if (vB) {
            uint2 o;
            o.x = pack2(a10[0] * s0B, a10[1] * s0B); o.y = pack2(a10[2] * s0B, a10[3] * s0B);
            *reinterpret_cast<uint2*>(Y0 + (size_t)rB * DDIM + col) = o;
        }
    }
}

// ---------------- bucket aggregate + LN epilogue ----------------
// One block per bucket (32 dst rows, exclusively owned). LDS f32 accumulator with
// column swizzle pos(c) = (c&3)*64 + (c>>2): all ds_add_f32 land at bank lane%32.
// mode 0: scale+LN -> out.  mode 1: scale -> partial (f32).  mode 2: scale+partial+LN -> out.
__global__ __launch_bounds__(256) void agg_k(
    const unsigned* __restrict__ recs, const int* __restrict__ cur,
    const __hip_bfloat16* __restrict__ Y,
    const float* __restrict__ partial,
    const float* __restrict__ gamma, const float* __restrict__ beta,
    const float* __restrict__ bias, float* __restrict__ out, int mode, int N) {
    __shared__ float acc[BROWS * DDIM];   // 32 KB
    __shared__ int cntl[BROWS];
    const int t = threadIdx.x, lane = t & 63, wid = t >> 6;
    const int b = blockIdx.x;
    const int dst0 = b * BROWS;

    // zero LDS
    {
        f4v* av = (f4v*)acc;
        #pragma unroll
        for (int i = 0; i < BROWS * DDIM / 4 / 256; ++i) av[t + i * 256] = (f4v){0.f,0.f,0.f,0.f};
        if (t < BROWS) cntl[t] = 0;
    }
    __syncthreads();

    const int n = min(cur[b], BCAP);
    const size_t base = (size_t)b * BCAP;
    for (int c0 = wid * 64; c0 < n; c0 += 256) {
        const int en = min(64, n - c0);
        unsigned rv = 0;
        if (lane < en) rv = recs[base + c0 + lane];
        #pragma unroll 4
        for (int j = 0; j < en; ++j) {
            const unsigned r = __shfl(rv, j);
            const int s = (int)(r & 0xffffu);
            const int dl = (int)(r >> 16);
            if (lane == 0) atomicAdd(&cntl[dl], 1);
            const uint2 v = reinterpret_cast<const uint2*>(Y + (size_t)s * DDIM)[lane];
            float* arow = acc + dl * DDIM;
            atomicAdd(&arow[lane],       bf2f(v.x & 0xffffu));
            atomicAdd(&arow[64 + lane],  bf2f(v.x >> 16));
            atomicAdd(&arow[128 + lane], bf2f(v.y & 0xffffu));
            atomicAdd(&arow[192 + lane], bf2f(v.y >> 16));
        }
    }
    __syncthreads();

    f4v g = (f4v){0.f,0.f,0.f,0.f}, be = g, bb = g;
    if (mode != 1) {
        g  = reinterpret_cast<const f4v*>(gamma)[lane];
        be = reinterpret_cast<const f4v*>(beta)[lane];
        bb = reinterpret_cast<const f4v*>(bias)[lane];
    }

    // each wave finalizes 8 rows
    for (int ri = 0; ri < BROWS / 4; ++ri) {
        const int r = wid * (BROWS / 4) + ri;
        const int row = dst0 + r;
        if (row >= N) break;
        const int cd = cntl[r];
        const float sc = rsqrtf((float)(cd < 1 ? 1 : cd));
        const float* arow = acc + r * DDIM;
        f4v a;
        a[0] = arow[lane] * sc;
        a[1] = arow[64 + lane] * sc;
        a[2] = arow[128 + lane] * sc;
        a[3] = arow[192 + lane] * sc;
        if (mode == 1) {
            reinterpret_cast<f4v*>(out + (size_t)row * DDIM)[lane] = a;
            continue;
        }
        if (mode == 2)
            a += reinterpret_cast<const f4v*>(partial + (size_t)row * DDIM)[lane];

        float s1 = a[0] + a[1] + a[2] + a[3];
        float s2 = a[0]*a[0] + a[1]*a[1] + a[2]*a[2] + a[3]*a[3];
        #pragma unroll
        for (int off = 1; off < 64; off <<= 1) {
            s1 += __shfl_xor(s1, off);
            s2 += __shfl_xor(s2, off);
        }
        const float mu = s1 * (1.f / 256.f);
        float var = s2 * (1.f / 256.f) - mu * mu;
        var = fmaxf(var, 0.f);
        const float rs = rsqrtf(var + 1e-5f);
        f4v o;
        #pragma unroll
        for (int j = 0; j < 4; ++j) {
            float v = (a[j] - mu) * rs * g[j] + be[j] + bb[j];
            o[j] = fmaxf(v, 0.f);
        }
        reinterpret_cast<f4v*>(out + (size_t)row * DDIM)[lane] = o;
    }
}

extern "C" void kernel_launch(void* const* d_in, const int* in_sizes, int n_in,
                              void* d_out, int out_size, void* d_ws, size_t ws_size,
                              hipStream_t stream) {
    const float* x_cell     = (const float*)d_in[0];
    const float* x_gene     = (const float*)d_in[1];
    const float* W_cg       = (const float*)d_in[2];
    const float* W_gc       = (const float*)d_in[3];
    const float* W_gg       = (const float*)d_in[4];
    const float* gamma_cell = (const float*)d_in[5];
    const float* beta_cell  = (const float*)d_in[6];
    const float* gamma_gene = (const float*)d_in[7];
    const float* beta_gene  = (const float*)d_in[8];
    const float* b_cell     = (const float*)d_in[9];
    const float* b_gene     = (const float*)d_in[10];
    const int* src_cg = (const int*)d_in[11];
    const int* dst_cg = (const int*)d_in[12];
    const int* src_gc = (const int*)d_in[13];
    const int* dst_gc = (const int*)d_in[14];
    const int* src_gg = (const int*)d_in[15];
    const int* dst_gg = (const int*)d_in[16];

    const int N = in_sizes[0] / DDIM;    // 50000
    const int E = in_sizes[11];          // 800000
    const int nb = (N + BROWS - 1) / BROWS;   // 1563 buckets

    // ---- workspace layout (~41 MB) ----
    char* wsb = (char*)d_ws;
    size_t off = 0;
    __hip_bfloat16* Y_gc = (__hip_bfloat16*)(wsb + off); off += (size_t)N * DDIM * 2;       // 25.6 MB
    unsigned* recs = (unsigned*)(wsb + off);             off += (size_t)3 * nb * BCAP * 4;  // 14.4 MB
    const size_t zeroOff = off;
    int* cs  = (int*)(wsb + off);                        off += (size_t)3 * N * 4;          // 600 KB
    int* cur = (int*)(wsb + off);                        off += (size_t)3 * nb * 4;         // 18.8 KB
    const size_t zeroBytes = off - zeroOff;
    __hip_bfloat16* Wt_gc = (__hip_bfloat16*)(wsb + off); off += (size_t)DDIM * DDIM * 2;
    __hip_bfloat16* Wt_cg = (__hip_bfloat16*)(wsb + off); off += (size_t)DDIM * DDIM * 2;
    __hip_bfloat16* Wt_gg = (__hip_bfloat16*)(wsb + off);

    unsigned* recs_gc = recs;
    unsigned* recs_cg = recs + (size_t)nb * BCAP;
    unsigned* recs_gg = recs + (size_t)2 * nb * BCAP;
    int* cs_gc = cs, *cs_cg = cs + N, *cs_gg = cs + 2 * N;
    int* cur_gc = cur, *cur_cg = cur + nb, *cur_gg = cur + 2 * nb;

    // Y_cg, Y_gg live in the d_out cell-half; consumed by agg(cg)/agg(gg) before
    // agg(gc) overwrites that region with the final cell output.
    float* out_cell = (float*)d_out;
    float* out_gene = out_cell + (size_t)N * DDIM;
    __hip_bfloat16* Y_cg = (__hip_bfloat16*)d_out;
    __hip_bfloat16* Y_gg = Y_cg + (size_t)N * DDIM;

    const int binBlocks  = (E + 255) / 256;
    const int gemmBlocks = (N + 127) / 128;

    transpose3_k<<<dim3(DDIM, 3), DDIM, 0, stream>>>(W_gc, W_cg, W_gg, Wt_gc, Wt_cg, Wt_gg);
    hipMemsetAsync(wsb + zeroOff, 0, zeroBytes, stream);

    bin_k<<<binBlocks, 256, 0, stream>>>(src_gc, dst_gc, src_cg, dst_cg, src_gg, dst_gg,
                                         cs, cur, recs, N, nb, E);

    gemm2_k<<<gemmBlocks, 256, 0, stream>>>(x_gene, Wt_gc, Wt_gg, cs_gc, cs_gg,
                                            Y_gc, Y_gg, N);
    gemm1_k<<<gemmBlocks, 256, 0, stream>>>(x_cell, Wt_cg, cs_cg, Y_cg, N);

    // gene: cg partial (f32) then gg add + LN
    agg_k<<<nb, 256, 0, stream>>>(recs_cg, cur_cg, Y_cg, nullptr,
                                  nullptr, nullptr, nullptr, out_gene, 1, N);
    agg_k<<<nb, 256, 0, stream>>>(recs_gg, cur_gg, Y_gg, out_gene,
                                  gamma_gene, beta_gene, b_gene, out_gene, 2, N);
    // cell: gc final (overwrites Y_cg/Y_gg region)
    agg_k<<<nb, 256, 0, stream>>>(recs_gc, cur_gc, Y_gc, nullptr,
                                  gamma_cell, beta_cell, b_cell, out_cell, 0, N);
}

// Round 6
// 565.726 us; speedup vs baseline: 7.0404x; 7.0404x over previous
//
#include <hip/hip_runtime.h>
#include <hip/hip_bf16.h>
#include <stdint.h>

#define DDIM 256
#define BROWS 32          // dst rows per bucket
#define BCAP 768          // record capacity per bucket (mean 512, +11 sigma)

typedef short s8v __attribute__((ext_vector_type(8)));
typedef float f4v __attribute__((ext_vector_type(4)));

__device__ __forceinline__ float bf2f(unsigned u) { return __uint_as_float(u << 16); }
__device__ __forceinline__ unsigned short f2bf(float f) {
    __hip_bfloat16 h = __float2bfloat16(f);
    return *reinterpret_cast<unsigned short*>(&h);
}
__device__ __forceinline__ unsigned pack2(float a, float b) {
    return (unsigned)f2bf(a) | ((unsigned)f2bf(b) << 16);
}

// ---------------- fused W transpose + cast: T[n][k] = bf16(W[k][n]) ----------------
__global__ void transpose3_k(const float* __restrict__ W0, const float* __restrict__ W1,
                             const float* __restrict__ W2, __hip_bfloat16* __restrict__ T0,
                             __hip_bfloat16* __restrict__ T1, __hip_bfloat16* __restrict__ T2) {
    const float* W = (blockIdx.y == 0) ? W0 : (blockIdx.y == 1) ? W1 : W2;
    __hip_bfloat16* T = (blockIdx.y == 0) ? T0 : (blockIdx.y == 1) ? T1 : T2;
    T[blockIdx.x * DDIM + threadIdx.x] = __float2bfloat16(W[threadIdx.x * DDIM + blockIdx.x]);
}

// ---------------- bin: src-degree count + bucket-append packed records ----------------
// record = src | (dst&31)<<16 (src < 65536); bucket = dst>>5. Bucket frontier lines stay
// L2-hot -> near-coalesced writebacks (vs 64B line per 4B scatter in a plain CSR fill).
__global__ void bin_k(const int* __restrict__ s0, const int* __restrict__ d0,
                      const int* __restrict__ s1, const int* __restrict__ d1,
                      const int* __restrict__ s2, const int* __restrict__ d2,
                      int* __restrict__ cs,            // 3 x n (deg_out per relation)
                      int* __restrict__ cur,           // 3 x nb cursors
                      unsigned* __restrict__ recs,     // 3 x nb x BCAP
                      int n, int nb, int E) {
    const int i = blockIdx.x * blockDim.x + threadIdx.x;
    if (i >= E) return;
    {
        const int s = s0[i], d = d0[i];
        atomicAdd(cs + s, 1);
        const int pos = atomicAdd(cur + (d >> 5), 1);
        if (pos < BCAP) recs[(size_t)(d >> 5) * BCAP + pos] = (unsigned)s | ((unsigned)(d & 31) << 16);
    }
    {
        const int s = s1[i], d = d1[i];
        atomicAdd(cs + n + s, 1);
        const int pos = atomicAdd(cur + nb + (d >> 5), 1);
        if (pos < BCAP) recs[((size_t)nb + (d >> 5)) * BCAP + pos] = (unsigned)s | ((unsigned)(d & 31) << 16);
    }
    {
        const int s = s2[i], d = d2[i];
        atomicAdd(cs + 2 * n + s, 1);
        const int pos = atomicAdd(cur + 2 * nb + (d >> 5), 1);
        if (pos < BCAP) recs[((size_t)2 * nb + (d >> 5)) * BCAP + pos] = (unsigned)s | ((unsigned)(d & 31) << 16);
    }
}

// ---------------- reorder: in-place counting sort of each bucket by local dst ----------------
// One block per (relation, bucket). Emits absolute row_beg / row_cnt for the gather.
__global__ __launch_bounds__(256) void reorder_k(
    unsigned* __restrict__ recs, const int* __restrict__ cur,
    int* __restrict__ row_beg, int* __restrict__ row_cnt, int N, int nb) {
    __shared__ unsigned lrec[BCAP];
    __shared__ int cnt[BROWS], curs[BROWS];
    const int b = blockIdx.x;            // 0 .. 3*nb-1
    const int rel = b / nb, lb = b % nb;
    const int t = threadIdx.x;
    const int n = min(cur[b], BCAP);
    const size_t base = (size_t)b * BCAP;

    if (t < BROWS) cnt[t] = 0;
    __syncthreads();
    for (int i = t; i < n; i += 256) {
        const unsigned r = recs[base + i];
        lrec[i] = r;
        atomicAdd(&cnt[r >> 16], 1);
    }
    __syncthreads();
    if (t < BROWS) {
        const int v = cnt[t];
        int incl = v;
        #pragma unroll
        for (int off = 1; off < BROWS; off <<= 1) {
            const int u = __shfl_up(incl, off);
            if (t >= off) incl += u;
        }
        curs[t] = incl - v;
        const int row = lb * BROWS + t;
        if (row < N) {
            row_cnt[(size_t)rel * N + row] = v;
            row_beg[(size_t)rel * N + row] = (int)base + incl - v;
        }
    }
    __syncthreads();
    for (int i = t; i < n; i += 256) {
        const unsigned r = lrec[i];
        const int pos = atomicAdd(&curs[r >> 16], 1);
        recs[base + pos] = r;
    }
}

// ---------------- dual-output GEMM: Y0 = bf16(s0(X@W0)), Y1 = bf16(s1(X@W1)) ----------------
__global__ __launch_bounds__(256) void gemm2_k(
    const float* __restrict__ X,
    const __hip_bfloat16* __restrict__ Wt0, const __hip_bfloat16* __restrict__ Wt1,
    const int* __restrict__ deg0, const int* __restrict__ deg1,
    __hip_bfloat16* __restrict__ Y0, __hip_bfloat16* __restrict__ Y1, int M) {
    const int lane = threadIdx.x & 63, wid = threadIdx.x >> 6;
    const int c = lane & 15, kb = lane >> 4;
    const int rA = blockIdx.x * 128 + wid * 32 + c;
    const int rB = rA + 16;
    const bool vA = rA < M, vB = rB < M;
    const int rAc = vA ? rA : (M - 1), rBc = vB ? rB : (M - 1);

    s8v xfA[8], xfB[8];
    const float* xA = X + (size_t)rAc * DDIM;
    const float* xB = X + (size_t)rBc * DDIM;
    #pragma unroll
    for (int ks = 0; ks < 8; ++ks) {
        const int k0 = ks * 32 + kb * 8;
        const f4v a0 = *reinterpret_cast<const f4v*>(xA + k0);
        const f4v a1 = *reinterpret_cast<const f4v*>(xA + k0 + 4);
        const f4v b0 = *reinterpret_cast<const f4v*>(xB + k0);
        const f4v b1 = *reinterpret_cast<const f4v*>(xB + k0 + 4);
        union { s8v v; unsigned short u[8]; } fa, fb;
        #pragma unroll
        for (int j = 0; j < 4; ++j) {
            fa.u[j] = f2bf(a0[j]); fa.u[4 + j] = f2bf(a1[j]);
            fb.u[j] = f2bf(b0[j]); fb.u[4 + j] = f2bf(b1[j]);
        }
        xfA[ks] = fa.v; xfB[ks] = fb.v;
    }

    const int dA0 = deg0[rAc], dB0 = deg0[rBc], dA1 = deg1[rAc], dB1 = deg1[rBc];
    const float s0A = rsqrtf((float)(dA0 < 1 ? 1 : dA0));
    const float s0B = rsqrtf((float)(dB0 < 1 ? 1 : dB0));
    const float s1A = rsqrtf((float)(dA1 < 1 ? 1 : dA1));
    const float s1B = rsqrtf((float)(dB1 < 1 ? 1 : dB1));

    #pragma unroll 2
    for (int nt = 0; nt < 16; ++nt) {
        const __hip_bfloat16* w0p = Wt0 + (size_t)(nt * 16 + c) * DDIM + kb * 8;
        const __hip_bfloat16* w1p = Wt1 + (size_t)(nt * 16 + c) * DDIM + kb * 8;
        s8v wf0[8], wf1[8];
        #pragma unroll
        for (int ks = 0; ks < 8; ++ks) {
            wf0[ks] = *reinterpret_cast<const s8v*>(w0p + ks * 32);
            wf1[ks] = *reinterpret_cast<const s8v*>(w1p + ks * 32);
        }
        f4v a00 = (f4v){0.f,0.f,0.f,0.f}, a01 = a00, a10 = a00, a11 = a00;
        #pragma unroll
        for (int ks = 0; ks < 8; ++ks) {
            a00 = __builtin_amdgcn_mfma_f32_16x16x32_bf16(wf0[ks], xfA[ks], a00, 0, 0, 0);
            a10 = __builtin_amdgcn_mfma_f32_16x16x32_bf16(wf0[ks], xfB[ks], a10, 0, 0, 0);
            a01 = __builtin_amdgcn_mfma_f32_16x16x32_bf16(wf1[ks], xfA[ks], a01, 0, 0, 0);
            a11 = __builtin_amdgcn_mfma_f32_16x16x32_bf16(wf1[ks], xfB[ks], a11, 0, 0, 0);
        }
        const int col = nt * 16 + kb * 4;
        if (vA) {
            uint2 o0, o1;
            o0.x = pack2(a00[0] * s0A, a00[1] * s0A); o0.y = pack2(a00[2] * s0A, a00[3] * s0A);
            o1.x = pack2(a01[0] * s1A, a01[1] * s1A); o1.y = pack2(a01[2] * s1A, a01[3] * s1A);
            *reinterpret_cast<uint2*>(Y0 + (size_t)rA * DDIM + col) = o0;
            *reinterpret_cast<uint2*>(Y1 + (size_t)rA * DDIM + col) = o1;
        }
        if (vB) {
            uint2 o0, o1;
            o0.x = pack2(a10[0] * s0B, a10[1] * s0B); o0.y = pack2(a10[2] * s0B, a10[3] * s0B);
            o1.x = pack2(a11[0] * s1B, a11[1] * s1B); o1.y = pack2(a11[2] * s1B, a11[3] * s1B);
            *reinterpret_cast<uint2*>(Y0 + (size_t)rB * DDIM + col) = o0;
            *reinterpret_cast<uint2*>(Y1 + (size_t)rB * DDIM + col) = o1;
        }
    }
}

// ---------------- single-output GEMM ----------------
__global__ __launch_bounds__(256) void gemm1_k(
    const float* __restrict__ X, const __hip_bfloat16* __restrict__ Wt0,
    const int* __restrict__ deg0, __hip_bfloat16* __restrict__ Y0, int M) {
    const int lane = threadIdx.x & 63, wid = threadIdx.x >> 6;
    const int c = lane & 15, kb = lane >> 4;
    const int rA = blockIdx.x * 128 + wid * 32 + c;
    const int rB = rA + 16;
    const bool vA = rA < M, vB = rB < M;
    const int rAc = vA ? rA : (M - 1), rBc = vB ? rB : (M - 1);

    s8v xfA[8], xfB[8];
    const float* xA = X + (size_t)rAc * DDIM;
    const float* xB = X + (size_t)rBc * DDIM;
    #pragma unroll
    for (int ks = 0; ks < 8; ++ks) {
        const int k0 = ks * 32 + kb * 8;
        const f4v a0 = *reinterpret_cast<const f4v*>(xA + k0);
        const f4v a1 = *reinterpret_cast<const f4v*>(xA + k0 + 4);
        const f4v b0 = *reinterpret_cast<const f4v*>(xB + k0);
        const f4v b1 = *reinterpret_cast<const f4v*>(xB + k0 + 4);
        union { s8v v; unsigned short u[8]; } fa, fb;
        #pragma unroll
        for (int j = 0; j < 4; ++j) {
            fa.u[j] = f2bf(a0[j]); fa.u[4 + j] = f2bf(a1[j]);
            fb.u[j] = f2bf(b0[j]); fb.u[4 + j] = f2bf(b1[j]);
        }
        xfA[ks] = fa.v; xfB[ks] = fb.v;
    }
    const int dA0 = deg0[rAc], dB0 = deg0[rBc];
    const float s0A = rsqrtf((float)(dA0 < 1 ? 1 : dA0));
    const float s0B = rsqrtf((float)(dB0 < 1 ? 1 : dB0));

    #pragma unroll 2
    for (int nt = 0; nt < 16; ++nt) {
        const __hip_bfloat16* w0p = Wt0 + (size_t)(nt * 16 + c) * DDIM + kb * 8;
        s8v wf0[8];
        #pragma unroll
        for (int ks = 0; ks < 8; ++ks) wf0[ks] = *reinterpret_cast<const s8v*>(w0p + ks * 32);
        f4v a00 = (f4v){0.f,0.f,0.f,0.f}, a10 = a00;
        #pragma unroll
        for (int ks = 0; ks < 8; ++ks) {
            a00 = __builtin_amdgcn_mfma_f32_16x16x32_bf16(wf0[ks], xfA[ks], a00, 0, 0, 0);
            a10 = __builtin_amdgcn_mfma_f32_16x16x32_bf16(wf0[ks], xfB[ks], a10, 0, 0, 0);
        }
        const int col = nt * 16 + kb * 4;
        if (vA) {
            uint2 o;
            o.x = pack2(a00[0] * s0A, a00[1] * s0A); o.y = pack2(a00[2] * s0A, a00[3] * s0A);
            *reinterpret_cast<uint2*>(Y0 + (size_t)rA * DDIM + col) = o;
        }
        if (vB) {
            uint2 o;
            o.x = pack2(a10[0] * s0B, a10[1] * s0B); o.y = pack2(a10[2] * s0B, a10[3] * s0B);
            *reinterpret_cast<uint2*>(Y0 + (size_t)rB * DDIM + col) = o;
        }
    }
}

// ---------------- gather helpers ----------------
__device__ __forceinline__ void addv(f4v& a, uint2 v) {
    a[0] += bf2f(v.x & 0xffffu);
    a[1] += bf2f(v.x >> 16);
    a[2] += bf2f(v.y & 0xffffu);
    a[3] += bf2f(v.y >> 16);
}

// lane-parallel record fetch (one coalesced load per 64 records), 4-wide MLP on Y rows
__device__ __forceinline__ f4v segsum(const unsigned* __restrict__ recs, int beg, int n,
                                      const __hip_bfloat16* __restrict__ Y, int lane) {
    f4v a = (f4v){0.f, 0.f, 0.f, 0.f};
    for (int j0 = 0; j0 < n; j0 += 64) {
        const int chunk = min(64, n - j0);
        unsigned rv = 0;
        if (lane < chunk) rv = recs[beg + j0 + lane];
        int t = 0;
        for (; t + 4 <= chunk; t += 4) {
            const int s0 = (int)(__shfl(rv, t)     & 0xffffu);
            const int s1 = (int)(__shfl(rv, t + 1) & 0xffffu);
            const int s2 = (int)(__shfl(rv, t + 2) & 0xffffu);
            const int s3 = (int)(__shfl(rv, t + 3) & 0xffffu);
            const uint2 v0 = reinterpret_cast<const uint2*>(Y + (size_t)s0 * DDIM)[lane];
            const uint2 v1 = reinterpret_cast<const uint2*>(Y + (size_t)s1 * DDIM)[lane];
            const uint2 v2 = reinterpret_cast<const uint2*>(Y + (size_t)s2 * DDIM)[lane];
            const uint2 v3 = reinterpret_cast<const uint2*>(Y + (size_t)s3 * DDIM)[lane];
            addv(a, v0); addv(a, v1); addv(a, v2); addv(a, v3);
        }
        for (; t < chunk; ++t) {
            const int s = (int)(__shfl(rv, t) & 0xffffu);
            addv(a, reinterpret_cast<const uint2*>(Y + (size_t)s * DDIM)[lane]);
        }
    }
    return a;
}

// ---------------- gather (+ optional 2nd relation) + LayerNorm + bias + ReLU ----------------
__global__ __launch_bounds__(256) void gather_ln_k(
    const unsigned* __restrict__ recs,
    const int* __restrict__ beg0, const int* __restrict__ cnt0,
    const __hip_bfloat16* __restrict__ Y0,
    const int* __restrict__ beg1, const int* __restrict__ cnt1,
    const __hip_bfloat16* __restrict__ Y1,          // beg1 == null -> single relation
    const float* __restrict__ gamma, const float* __restrict__ beta,
    const float* __restrict__ bias, float* __restrict__ out, int n_dst) {
    const int lane = threadIdx.x & 63, wid = threadIdx.x >> 6;
    const int row = blockIdx.x * 4 + wid;
    if (row >= n_dst) return;

    const int n0 = cnt0[row];
    f4v a = segsum(recs, beg0[row], n0, Y0, lane);
    a *= rsqrtf((float)(n0 < 1 ? 1 : n0));
    if (beg1 != nullptr) {
        const int n1 = cnt1[row];
        f4v a1 = segsum(recs, beg1[row], n1, Y1, lane);
        a += a1 * rsqrtf((float)(n1 < 1 ? 1 : n1));
    }

    float s1 = a[0] + a[1] + a[2] + a[3];
    float s2 = a[0]*a[0] + a[1]*a[1] + a[2]*a[2] + a[3]*a[3];
    #pragma unroll
    for (int off = 1; off < 64; off <<= 1) {
        s1 += __shfl_xor(s1, off);
        s2 += __shfl_xor(s2, off);
    }
    const float mu = s1 * (1.f / 256.f);
    float var = s2 * (1.f / 256.f) - mu * mu;
    var = fmaxf(var, 0.f);
    const float rs = rsqrtf(var + 1e-5f);

    const f4v g  = reinterpret_cast<const f4v*>(gamma)[lane];
    const f4v be = reinterpret_cast<const f4v*>(beta)[lane];
    const f4v bb = reinterpret_cast<const f4v*>(bias)[lane];
    f4v o;
    #pragma unroll
    for (int j = 0; j < 4; ++j) {
        float v = (a[j] - mu) * rs * g[j] + be[j] + bb[j];
        o[j] = fmaxf(v, 0.f);
    }
    reinterpret_cast<f4v*>(out + (size_t)row * DDIM)[lane] = o;
}

extern "C" void kernel_launch(void* const* d_in, const int* in_sizes, int n_in,
                              void* d_out, int out_size, void* d_ws, size_t ws_size,
                              hipStream_t stream) {
    const float* x_cell     = (const float*)d_in[0];
    const float* x_gene     = (const float*)d_in[1];
    const float* W_cg       = (const float*)d_in[2];
    const float* W_gc       = (const float*)d_in[3];
    const float* W_gg       = (const float*)d_in[4];
    const float* gamma_cell = (const float*)d_in[5];
    const float* beta_cell  = (const float*)d_in[6];
    const float* gamma_gene = (const float*)d_in[7];
    const float* beta_gene  = (const float*)d_in[8];
    const float* b_cell     = (const float*)d_in[9];
    const float* b_gene     = (const float*)d_in[10];
    const int* src_cg = (const int*)d_in[11];
    const int* dst_cg = (const int*)d_in[12];
    const int* src_gc = (const int*)d_in[13];
    const int* dst_gc = (const int*)d_in[14];
    const int* src_gg = (const int*)d_in[15];
    const int* dst_gg = (const int*)d_in[16];

    const int N = in_sizes[0] / DDIM;    // 50000
    const int E = in_sizes[11];          // 800000
    const int nb = (N + BROWS - 1) / BROWS;   // 1563 buckets

    // ---- workspace layout (~43 MB) ----
    char* wsb = (char*)d_ws;
    size_t off = 0;
    __hip_bfloat16* Y_gc = (__hip_bfloat16*)(wsb + off); off += (size_t)N * DDIM * 2;       // 25.6 MB
    unsigned* recs = (unsigned*)(wsb + off);             off += (size_t)3 * nb * BCAP * 4;  // 14.4 MB
    int* row_beg = (int*)(wsb + off);                    off += (size_t)3 * N * 4;          // 600 KB
    int* row_cnt = (int*)(wsb + off);                    off += (size_t)3 * N * 4;          // 600 KB
    const size_t zeroOff = off;
    int* cs  = (int*)(wsb + off);                        off += (size_t)3 * N * 4;          // 600 KB
    int* cur = (int*)(wsb + off);                        off += (size_t)3 * nb * 4;         // 18.8 KB
    const size_t zeroBytes = off - zeroOff;
    __hip_bfloat16* Wt_gc = (__hip_bfloat16*)(wsb + off); off += (size_t)DDIM * DDIM * 2;
    __hip_bfloat16* Wt_cg = (__hip_bfloat16*)(wsb + off); off += (size_t)DDIM * DDIM * 2;
    __hip_bfloat16* Wt_gg = (__hip_bfloat16*)(wsb + off);

    int* cs_gc = cs, *cs_cg = cs + N, *cs_gg = cs + 2 * N;
    int* beg_gc = row_beg, *beg_cg = row_beg + N, *beg_gg = row_beg + 2 * N;
    int* cnt_gc = row_cnt, *cnt_cg = row_cnt + N, *cnt_gg = row_cnt + 2 * N;

    // Y_cg, Y_gg live in the d_out cell-half; consumed by the gene gather before
    // the cell gather overwrites that region with the final cell output.
    float* out_cell = (float*)d_out;
    float* out_gene = out_cell + (size_t)N * DDIM;
    __hip_bfloat16* Y_cg = (__hip_bfloat16*)d_out;
    __hip_bfloat16* Y_gg = Y_cg + (size_t)N * DDIM;

    const int binBlocks  = (E + 255) / 256;
    const int gemmBlocks = (N + 127) / 128;
    const int gatherBlocks = (N + 3) / 4;

    transpose3_k<<<dim3(DDIM, 3), DDIM, 0, stream>>>(W_gc, W_cg, W_gg, Wt_gc, Wt_cg, Wt_gg);
    hipMemsetAsync(wsb + zeroOff, 0, zeroBytes, stream);

    bin_k<<<binBlocks, 256, 0, stream>>>(src_gc, dst_gc, src_cg, dst_cg, src_gg, dst_gg,
                                         cs, cur, recs, N, nb, E);
    reorder_k<<<3 * nb, 256, 0, stream>>>(recs, cur, row_beg, row_cnt, N, nb);

    gemm2_k<<<gemmBlocks, 256, 0, stream>>>(x_gene, Wt_gc, Wt_gg, cs_gc, cs_gg,
                                            Y_gc, Y_gg, N);
    gemm1_k<<<gemmBlocks, 256, 0, stream>>>(x_cell, Wt_cg, cs_cg, Y_cg, N);

    // gene: cg + gg fused gather + LN
    gather_ln_k<<<gatherBlocks, 256, 0, stream>>>(recs, beg_cg, cnt_cg, Y_cg,
                                                  beg_gg, cnt_gg, Y_gg,
                                                  gamma_gene, beta_gene, b_gene, out_gene, N);
    // cell: gc gather + LN (overwrites Y_cg/Y_gg region)
    gather_ln_k<<<gatherBlocks, 256, 0, stream>>>(recs, beg_gc, cnt_gc, Y_gc,
                                                  nullptr, nullptr, nullptr,
                                                  gamma_cell, beta_cell, b_cell, out_cell, N);
}

// Round 7
// 531.349 us; speedup vs baseline: 7.4959x; 1.0647x over previous
//
#include <hip/hip_runtime.h>
#include <hip/hip_bf16.h>
#include <stdint.h>

#define DDIM 256
#define BROWS 32          // dst rows per bucket
#define NSHARD 8          // shards per bucket (≈ XCDs)
#define SCAP 128          // record capacity per shard-bucket (mean 64, +8 sigma)

typedef short s8v __attribute__((ext_vector_type(8)));
typedef float f4v __attribute__((ext_vector_type(4)));

__device__ __forceinline__ float bf2f(unsigned u) { return __uint_as_float(u << 16); }
__device__ __forceinline__ unsigned short f2bf(float f) {
    __hip_bfloat16 h = __float2bfloat16(f);
    return *reinterpret_cast<unsigned short*>(&h);
}
__device__ __forceinline__ unsigned pack2(float a, float b) {
    return (unsigned)f2bf(a) | ((unsigned)f2bf(b) << 16);
}

// ---------------- fused W transpose + cast: T[n][k] = bf16(W[k][n]) ----------------
__global__ void transpose3_k(const float* __restrict__ W0, const float* __restrict__ W1,
                             const float* __restrict__ W2, __hip_bfloat16* __restrict__ T0,
                             __hip_bfloat16* __restrict__ T1, __hip_bfloat16* __restrict__ T2) {
    const float* W = (blockIdx.y == 0) ? W0 : (blockIdx.y == 1) ? W1 : W2;
    __hip_bfloat16* T = (blockIdx.y == 0) ? T0 : (blockIdx.y == 1) ? T1 : T2;
    T[blockIdx.x * DDIM + threadIdx.x] = __float2bfloat16(W[threadIdx.x * DDIM + blockIdx.x]);
}

// ---------------- bin (XCD-sharded): deg_out count + bucket-append ----------------
// shard = blockIdx&7 ≈ XCD id (round-robin dispatch): cursor atomics stay in the local
// L2 (no cross-XCD line bouncing) and each XCD's record slice (2.4 MB) is L2-resident,
// so record lines fill completely before writeback.
__global__ void bin_k(const int* __restrict__ s0, const int* __restrict__ d0,
                      const int* __restrict__ s1, const int* __restrict__ d1,
                      const int* __restrict__ s2, const int* __restrict__ d2,
                      int* __restrict__ cs_shard,      // [NSHARD][3n]
                      int* __restrict__ cur,           // [3nb][NSHARD]
                      unsigned* __restrict__ recs,     // [3nb][NSHARD][SCAP]
                      int n, int nb, int E) {
    const int i = blockIdx.x * blockDim.x + threadIdx.x;
    if (i >= E) return;
    const int sh = blockIdx.x & (NSHARD - 1);
    int* csb = cs_shard + (size_t)sh * 3 * n;
    {
        const int s = s0[i], d = d0[i];
        atomicAdd(csb + s, 1);
        const size_t sb = (size_t)(d >> 5) * NSHARD + sh;
        const int pos = atomicAdd(cur + sb, 1);
        if (pos < SCAP) recs[sb * SCAP + pos] = (unsigned)s | ((unsigned)(d & 31) << 16);
    }
    {
        const int s = s1[i], d = d1[i];
        atomicAdd(csb + n + s, 1);
        const size_t sb = ((size_t)nb + (d >> 5)) * NSHARD + sh;
        const int pos = atomicAdd(cur + sb, 1);
        if (pos < SCAP) recs[sb * SCAP + pos] = (unsigned)s | ((unsigned)(d & 31) << 16);
    }
    {
        const int s = s2[i], d = d2[i];
        atomicAdd(csb + 2 * n + s, 1);
        const size_t sb = ((size_t)2 * nb + (d >> 5)) * NSHARD + sh;
        const int pos = atomicAdd(cur + sb, 1);
        if (pos < SCAP) recs[sb * SCAP + pos] = (unsigned)s | ((unsigned)(d & 31) << 16);
    }
}

// ---------------- fold sharded deg_out ----------------
__global__ void reduce_cs_k(const int* __restrict__ cs_shard, int* __restrict__ cs, int n3) {
    const int i = blockIdx.x * blockDim.x + threadIdx.x;
    if (i >= n3) return;
    int v = 0;
    #pragma unroll
    for (int s = 0; s < NSHARD; ++s) v += cs_shard[(size_t)s * n3 + i];
    cs[i] = v;
}

// ---------------- reorder: merge 8 shards + counting-sort by local dst, in place ----------------
// One block per (relation, bucket). Emits absolute row_beg / row_cnt for the gather.
__global__ __launch_bounds__(256) void reorder_k(
    unsigned* __restrict__ recs, const int* __restrict__ cur,
    int* __restrict__ row_beg, int* __restrict__ row_cnt, int N, int nb) {
    __shared__ unsigned lrec[NSHARD * SCAP];
    __shared__ int cnt[BROWS], curs[BROWS], shoff[NSHARD + 1];
    const int b = blockIdx.x;            // 0 .. 3*nb-1
    const int rel = b / nb, lb = b % nb;
    const int t = threadIdx.x;
    const size_t base = (size_t)b * NSHARD * SCAP;

    if (t < BROWS) cnt[t] = 0;
    if (t == 0) {
        int acc = 0;
        #pragma unroll
        for (int s = 0; s < NSHARD; ++s) {
            shoff[s] = acc;
            acc += min(cur[(size_t)b * NSHARD + s], SCAP);
        }
        shoff[NSHARD] = acc;
    }
    __syncthreads();
    const int n = shoff[NSHARD];
    // compact-load all shards into LDS + histogram
    #pragma unroll
    for (int s = 0; s < NSHARD; ++s) {
        const int c0 = shoff[s], c1 = shoff[s + 1];
        for (int i = c0 + t; i < c1; i += 256) {
            const unsigned r = recs[base + (size_t)s * SCAP + (i - c0)];
            lrec[i] = r;
            atomicAdd(&cnt[r >> 16], 1);
        }
    }
    __syncthreads();
    if (t < BROWS) {
        const int v = cnt[t];
        int incl = v;
        #pragma unroll
        for (int off = 1; off < BROWS; off <<= 1) {
            const int u = __shfl_up(incl, off);
            if (t >= off) incl += u;
        }
        curs[t] = incl - v;
        const int row = lb * BROWS + t;
        if (row < N) {
            row_cnt[(size_t)rel * N + row] = v;
            row_beg[(size_t)rel * N + row] = (int)base + incl - v;
        }
    }
    __syncthreads();
    for (int i = t; i < n; i += 256) {
        const unsigned r = lrec[i];
        const int pos = atomicAdd(&curs[r >> 16], 1);
        recs[base + pos] = r;
    }
}

// ---------------- dual-output GEMM: Y0 = bf16(s0(X@W0)), Y1 = bf16(s1(X@W1)) ----------------
__global__ __launch_bounds__(256) void gemm2_k(
    const float* __restrict__ X,
    const __hip_bfloat16* __restrict__ Wt0, const __hip_bfloat16* __restrict__ Wt1,
    const int* __restrict__ deg0, const int* __restrict__ deg1,
    __hip_bfloat16* __restrict__ Y0, __hip_bfloat16* __restrict__ Y1, int M) {
    const int lane = threadIdx.x & 63, wid = threadIdx.x >> 6;
    const int c = lane & 15, kb = lane >> 4;
    const int rA = blockIdx.x * 128 + wid * 32 + c;
    const int rB = rA + 16;
    const bool vA = rA < M, vB = rB < M;
    const int rAc = vA ? rA : (M - 1), rBc = vB ? rB : (M - 1);

    s8v xfA[8], xfB[8];
    const float* xA = X + (size_t)rAc * DDIM;
    const float* xB = X + (size_t)rBc * DDIM;
    #pragma unroll
    for (int ks = 0; ks < 8; ++ks) {
        const int k0 = ks * 32 + kb * 8;
        const f4v a0 = *reinterpret_cast<const f4v*>(xA + k0);
        const f4v a1 = *reinterpret_cast<const f4v*>(xA + k0 + 4);
        const f4v b0 = *reinterpret_cast<const f4v*>(xB + k0);
        const f4v b1 = *reinterpret_cast<const f4v*>(xB + k0 + 4);
        union { s8v v; unsigned short u[8]; } fa, fb;
        #pragma unroll
        for (int j = 0; j < 4; ++j) {
            fa.u[j] = f2bf(a0[j]); fa.u[4 + j] = f2bf(a1[j]);
            fb.u[j] = f2bf(b0[j]); fb.u[4 + j] = f2bf(b1[j]);
        }
        xfA[ks] = fa.v; xfB[ks] = fb.v;
    }

    const int dA0 = deg0[rAc], dB0 = deg0[rBc], dA1 = deg1[rAc], dB1 = deg1[rBc];
    const float s0A = rsqrtf((float)(dA0 < 1 ? 1 : dA0));
    const float s0B = rsqrtf((float)(dB0 < 1 ? 1 : dB0));
    const float s1A = rsqrtf((float)(dA1 < 1 ? 1 : dA1));
    const float s1B = rsqrtf((float)(dB1 < 1 ? 1 : dB1));

    #pragma unroll 2
    for (int nt = 0; nt < 16; ++nt) {
        const __hip_bfloat16* w0p = Wt0 + (size_t)(nt * 16 + c) * DDIM + kb * 8;
        const __hip_bfloat16* w1p = Wt1 + (size_t)(nt * 16 + c) * DDIM + kb * 8;
        s8v wf0[8], wf1[8];
        #pragma unroll
        for (int ks = 0; ks < 8; ++ks) {
            wf0[ks] = *reinterpret_cast<const s8v*>(w0p + ks * 32);
            wf1[ks] = *reinterpret_cast<const s8v*>(w1p + ks * 32);
        }
        f4v a00 = (f4v){0.f,0.f,0.f,0.f}, a01 = a00, a10 = a00, a11 = a00;
        #pragma unroll
        for (int ks = 0; ks < 8; ++ks) {
            a00 = __builtin_amdgcn_mfma_f32_16x16x32_bf16(wf0[ks], xfA[ks], a00, 0, 0, 0);
            a10 = __builtin_amdgcn_mfma_f32_16x16x32_bf16(wf0[ks], xfB[ks], a10, 0, 0, 0);
            a01 = __builtin_amdgcn_mfma_f32_16x16x32_bf16(wf1[ks], xfA[ks], a01, 0, 0, 0);
            a11 = __builtin_amdgcn_mfma_f32_16x16x32_bf16(wf1[ks], xfB[ks], a11, 0, 0, 0);
        }
        const int col = nt * 16 + kb * 4;
        if (vA) {
            uint2 o0, o1;
            o0.x = pack2(a00[0] * s0A, a00[1] * s0A); o0.y = pack2(a00[2] * s0A, a00[3] * s0A);
            o1.x = pack2(a01[0] * s1A, a01[1] * s1A); o1.y = pack2(a01[2] * s1A, a01[3] * s1A);
            *reinterpret_cast<uint2*>(Y0 + (size_t)rA * DDIM + col) = o0;
            *reinterpret_cast<uint2*>(Y1 + (size_t)rA * DDIM + col) = o1;
        }
        if (vB) {
            uint2 o0, o1;
            o0.x = pack2(a10[0] * s0B, a10[1] * s0B); o0.y = pack2(a10[2] * s0B, a10[3] * s0B);
            o1.x = pack2(a11[0] * s1B, a11[1] * s1B); o1.y = pack2(a11[2] * s1B, a11[3] * s1B);
            *reinterpret_cast<uint2*>(Y0 + (size_t)rB * DDIM + col) = o0;
            *reinterpret_cast<uint2*>(Y1 + (size_t)rB * DDIM + col) = o1;
        }
    }
}

// ---------------- single-output GEMM ----------------
__global__ __launch_bounds__(256) void gemm1_k(
    const float* __restrict__ X, const __hip_bfloat16* __restrict__ Wt0,
    const int* __restrict__ deg0, __hip_bfloat16* __restrict__ Y0, int M) {
    const int lane = threadIdx.x & 63, wid = threadIdx.x >> 6;
    const int c = lane & 15, kb = lane >> 4;
    const int rA = blockIdx.x * 128 + wid * 32 + c;
    const int rB = rA + 16;
    const bool vA = rA < M, vB = rB < M;
    const int rAc = vA ? rA : (M - 1), rBc = vB ? rB : (M - 1);

    s8v xfA[8], xfB[8];
    const float* xA = X + (size_t)rAc * DDIM;
    const float* xB = X + (size_t)rBc * DDIM;
    #pragma unroll
    for (int ks = 0; ks < 8; ++ks) {
        const int k0 = ks * 32 + kb * 8;
        const f4v a0 = *reinterpret_cast<const f4v*>(xA + k0);
        const f4v a1 = *reinterpret_cast<const f4v*>(xA + k0 + 4);
        const f4v b0 = *reinterpret_cast<const f4v*>(xB + k0);
        const f4v b1 = *reinterpret_cast<const f4v*>(xB + k0 + 4);
        union { s8v v; unsigned short u[8]; } fa, fb;
        #pragma unroll
        for (int j = 0; j < 4; ++j) {
            fa.u[j] = f2bf(a0[j]); fa.u[4 + j] = f2bf(a1[j]);
            fb.u[j] = f2bf(b0[j]); fb.u[4 + j] = f2bf(b1[j]);
        }
        xfA[ks] = fa.v; xfB[ks] = fb.v;
    }
    const int dA0 = deg0[rAc], dB0 = deg0[rBc];
    const float s0A = rsqrtf((float)(dA0 < 1 ? 1 : dA0));
    const float s0B = rsqrtf((float)(dB0 < 1 ? 1 : dB0));

    #pragma unroll 2
    for (int nt = 0; nt < 16; ++nt) {
        const __hip_bfloat16* w0p = Wt0 + (size_t)(nt * 16 + c) * DDIM + kb * 8;
        s8v wf0[8];
        #pragma unroll
        for (int ks = 0; ks < 8; ++ks) wf0[ks] = *reinterpret_cast<const s8v*>(w0p + ks * 32);
        f4v a00 = (f4v){0.f,0.f,0.f,0.f}, a10 = a00;
        #pragma unroll
        for (int ks = 0; ks < 8; ++ks) {
            a00 = __builtin_amdgcn_mfma_f32_16x16x32_bf16(wf0[ks], xfA[ks], a00, 0, 0, 0);
            a10 = __builtin_amdgcn_mfma_f32_16x16x32_bf16(wf0[ks], xfB[ks], a10, 0, 0, 0);
        }
        const int col = nt * 16 + kb * 4;
        if (vA) {
            uint2 o;
            o.x = pack2(a00[0] * s0A, a00[1] * s0A); o.y = pack2(a00[2] * s0A, a00[3] * s0A);
            *reinterpret_cast<uint2*>(Y0 + (size_t)rA * DDIM + col) = o;
        }
        if (vB) {
            uint2 o;
            o.x = pack2(a10[0] * s0B, a10[1] * s0B); o.y = pack2(a10[2] * s0B, a10[3] * s0B);
            *reinterpret_cast<uint2*>(Y0 + (size_t)rB * DDIM + col) = o;
        }
    }
}

// ---------------- gather helpers ----------------
__device__ __forceinline__ void addv(f4v& a, uint2 v) {
    a[0] += bf2f(v.x & 0xffffu);
    a[1] += bf2f(v.x >> 16);
    a[2] += bf2f(v.y & 0xffffu);
    a[3] += bf2f(v.y >> 16);
}

// lane-parallel record fetch (one coalesced load per 64 records), 4-wide MLP on Y rows
__device__ __forceinline__ f4v segsum(const unsigned* __restrict__ recs, int beg, int n,
                                      const __hip_bfloat16* __restrict__ Y, int lane) {
    f4v a = (f4v){0.f, 0.f, 0.f, 0.f};
    for (int j0 = 0; j0 < n; j0 += 64) {
        const int chunk = min(64, n - j0);
        unsigned rv = 0;
        if (lane < chunk) rv = recs[beg + j0 + lane];
        int t = 0;
        for (; t + 4 <= chunk; t += 4) {
            const int s0 = (int)(__shfl(rv, t)     & 0xffffu);
            const int s1 = (int)(__shfl(rv, t + 1) & 0xffffu);
            const int s2 = (int)(__shfl(rv, t + 2) & 0xffffu);
            const int s3 = (int)(__shfl(rv, t + 3) & 0xffffu);
            const uint2 v0 = reinterpret_cast<const uint2*>(Y + (size_t)s0 * DDIM)[lane];
            const uint2 v1 = reinterpret_cast<const uint2*>(Y + (size_t)s1 * DDIM)[lane];
            const uint2 v2 = reinterpret_cast<const uint2*>(Y + (size_t)s2 * DDIM)[lane];
            const uint2 v3 = reinterpret_cast<const uint2*>(Y + (size_t)s3 * DDIM)[lane];
            addv(a, v0); addv(a, v1); addv(a, v2); addv(a, v3);
        }
        for (; t < chunk; ++t) {
            const int s = (int)(__shfl(rv, t) & 0xffffu);
            addv(a, reinterpret_cast<const uint2*>(Y + (size_t)s * DDIM)[lane]);
        }
    }
    return a;
}

// ---------------- gather (+ optional 2nd relation) + LayerNorm + bias + ReLU ----------------
__global__ __launch_bounds__(256) void gather_ln_k(
    const unsigned* __restrict__ recs,
    const int* __restrict__ beg0, const int* __restrict__ cnt0,
    const __hip_bfloat16* __restrict__ Y0,
    const int* __restrict__ beg1, const int* __restrict__ cnt1,
    const __hip_bfloat16* __restrict__ Y1,          // beg1 == null -> single relation
    const float* __restrict__ gamma, const float* __restrict__ beta,
    const float* __restrict__ bias, float* __restrict__ out, int n_dst) {
    const int lane = threadIdx.x & 63, wid = threadIdx.x >> 6;
    const int row = blockIdx.x * 4 + wid;
    if (row >= n_dst) return;

    const int n0 = cnt0[row];
    f4v a = segsum(recs, beg0[row], n0, Y0, lane);
    a *= rsqrtf((float)(n0 < 1 ? 1 : n0));
    if (beg1 != nullptr) {
        const int n1 = cnt1[row];
        f4v a1 = segsum(recs, beg1[row], n1, Y1, lane);
        a += a1 * rsqrtf((float)(n1 < 1 ? 1 : n1));
    }

    float s1 = a[0] + a[1] + a[2] + a[3];
    float s2 = a[0]*a[0] + a[1]*a[1] + a[2]*a[2] + a[3]*a[3];
    #pragma unroll
    for (int off = 1; off < 64; off <<= 1) {
        s1 += __shfl_xor(s1, off);
        s2 += __shfl_xor(s2, off);
    }
    const float mu = s1 * (1.f / 256.f);
    float var = s2 * (1.f / 256.f) - mu * mu;
    var = fmaxf(var, 0.f);
    const float rs = rsqrtf(var + 1e-5f);

    const f4v g  = reinterpret_cast<const f4v*>(gamma)[lane];
    const f4v be = reinterpret_cast<const f4v*>(beta)[lane];
    const f4v bb = reinterpret_cast<const f4v*>(bias)[lane];
    f4v o;
    #pragma unroll
    for (int j = 0; j < 4; ++j) {
        float v = (a[j] - mu) * rs * g[j] + be[j] + bb[j];
        o[j] = fmaxf(v, 0.f);
    }
    reinterpret_cast<f4v*>(out + (size_t)row * DDIM)[lane] = o;
}

extern "C" void kernel_launch(void* const* d_in, const int* in_sizes, int n_in,
                              void* d_out, int out_size, void* d_ws, size_t ws_size,
                              hipStream_t stream) {
    const float* x_cell     = (const float*)d_in[0];
    const float* x_gene     = (const float*)d_in[1];
    const float* W_cg       = (const float*)d_in[2];
    const float* W_gc       = (const float*)d_in[3];
    const float* W_gg       = (const float*)d_in[4];
    const float* gamma_cell = (const float*)d_in[5];
    const float* beta_cell  = (const float*)d_in[6];
    const float* gamma_gene = (const float*)d_in[7];
    const float* beta_gene  = (const float*)d_in[8];
    const float* b_cell     = (const float*)d_in[9];
    const float* b_gene     = (const float*)d_in[10];
    const int* src_cg = (const int*)d_in[11];
    const int* dst_cg = (const int*)d_in[12];
    const int* src_gc = (const int*)d_in[13];
    const int* dst_gc = (const int*)d_in[14];
    const int* src_gg = (const int*)d_in[15];
    const int* dst_gg = (const int*)d_in[16];

    const int N = in_sizes[0] / DDIM;    // 50000
    const int E = in_sizes[11];          // 800000
    const int nb = (N + BROWS - 1) / BROWS;   // 1563 buckets

    // ---- workspace layout (~52 MB) ----
    char* wsb = (char*)d_ws;
    size_t off = 0;
    __hip_bfloat16* Y_gc = (__hip_bfloat16*)(wsb + off); off += (size_t)N * DDIM * 2;            // 25.6 MB
    unsigned* recs = (unsigned*)(wsb + off);             off += (size_t)3 * nb * NSHARD * SCAP * 4; // 19.2 MB
    int* row_beg = (int*)(wsb + off);                    off += (size_t)3 * N * 4;               // 600 KB
    int* row_cnt = (int*)(wsb + off);                    off += (size_t)3 * N * 4;               // 600 KB
    int* cs      = (int*)(wsb + off);                    off += (size_t)3 * N * 4;               // 600 KB
    const size_t zeroOff = off;
    int* cs_shard = (int*)(wsb + off);                   off += (size_t)NSHARD * 3 * N * 4;      // 4.8 MB
    int* cur      = (int*)(wsb + off);                   off += (size_t)3 * nb * NSHARD * 4;     // 150 KB
    const size_t zeroBytes = off - zeroOff;
    __hip_bfloat16* Wt_gc = (__hip_bfloat16*)(wsb + off); off += (size_t)DDIM * DDIM * 2;
    __hip_bfloat16* Wt_cg = (__hip_bfloat16*)(wsb + off); off += (size_t)DDIM * DDIM * 2;
    __hip_bfloat16* Wt_gg = (__hip_bfloat16*)(wsb + off);

    int* cs_gc = cs, *cs_cg = cs + N, *cs_gg = cs + 2 * N;
    int* beg_gc = row_beg, *beg_cg = row_beg + N, *beg_gg = row_beg + 2 * N;
    int* cnt_gc = row_cnt, *cnt_cg = row_cnt + N, *cnt_gg = row_cnt + 2 * N;

    // Y_cg, Y_gg live in the d_out cell-half; consumed by the gene gather before
    // the cell gather overwrites that region with the final cell output.
    float* out_cell = (float*)d_out;
    float* out_gene = out_cell + (size_t)N * DDIM;
    __hip_bfloat16* Y_cg = (__hip_bfloat16*)d_out;
    __hip_bfloat16* Y_gg = Y_cg + (size_t)N * DDIM;

    const int binBlocks  = (E + 255) / 256;
    const int gemmBlocks = (N + 127) / 128;
    const int gatherBlocks = (N + 3) / 4;

    transpose3_k<<<dim3(DDIM, 3), DDIM, 0, stream>>>(W_gc, W_cg, W_gg, Wt_gc, Wt_cg, Wt_gg);
    hipMemsetAsync(wsb + zeroOff, 0, zeroBytes, stream);

    bin_k<<<binBlocks, 256, 0, stream>>>(src_gc, dst_gc, src_cg, dst_cg, src_gg, dst_gg,
                                         cs_shard, cur, recs, N, nb, E);
    reduce_cs_k<<<(3 * N + 255) / 256, 256, 0, stream>>>(cs_shard, cs, 3 * N);
    reorder_k<<<3 * nb, 256, 0, stream>>>(recs, cur, row_beg, row_cnt, N, nb);

    gemm2_k<<<gemmBlocks, 256, 0, stream>>>(x_gene, Wt_gc, Wt_gg, cs_gc, cs_gg,
                                            Y_gc, Y_gg, N);
    gemm1_k<<<gemmBlocks, 256, 0, stream>>>(x_cell, Wt_cg, cs_cg, Y_cg, N);

    // gene: cg + gg fused gather + LN
    gather_ln_k<<<gatherBlocks, 256, 0, stream>>>(recs, beg_cg, cnt_cg, Y_cg,
                                                  beg_gg, cnt_gg, Y_gg,
                                                  gamma_gene, beta_gene, b_gene, out_gene, N);
    // cell: gc gather + LN (overwrites Y_cg/Y_gg region)
    gather_ln_k<<<gatherBlocks, 256, 0, stream>>>(recs, beg_gc, cnt_gc, Y_gc,
                                                  nullptr, nullptr, nullptr,
                                                  gamma_cell, beta_cell, b_cell, out_cell, N);
}

// Round 8
// 421.287 us; speedup vs baseline: 9.4542x; 1.2613x over previous
//
#include <hip/hip_runtime.h>
#include <hip/hip_bf16.h>
#include <stdint.h>

#define DDIM 256
#define NSHARD 8          // shards for deg_out atomics
#define T1 4096           // edges per bin1 block
#define NCPAD 128         // padded coarse-bin count (dst>>9, 512 rows/bin)
#define CCAP 9216         // record capacity per (rel, coarse bin); mean 8192, +11 sigma

typedef short s8v __attribute__((ext_vector_type(8)));
typedef float f4v __attribute__((ext_vector_type(4)));

__device__ __forceinline__ float bf2f(unsigned u) { return __uint_as_float(u << 16); }
__device__ __forceinline__ unsigned short f2bf(float f) {
    __hip_bfloat16 h = __float2bfloat16(f);
    return *reinterpret_cast<unsigned short*>(&h);
}
__device__ __forceinline__ unsigned pack2(float a, float b) {
    return (unsigned)f2bf(a) | ((unsigned)f2bf(b) << 16);
}

// ---------------- fused W transpose + cast: T[n][k] = bf16(W[k][n]) ----------------
__global__ void transpose3_k(const float* __restrict__ W0, const float* __restrict__ W1,
                             const float* __restrict__ W2, __hip_bfloat16* __restrict__ T0,
                             __hip_bfloat16* __restrict__ T1v, __hip_bfloat16* __restrict__ T2) {
    const float* W = (blockIdx.y == 0) ? W0 : (blockIdx.y == 1) ? W1 : W2;
    __hip_bfloat16* T = (blockIdx.y == 0) ? T0 : (blockIdx.y == 1) ? T1v : T2;
    T[blockIdx.x * DDIM + threadIdx.x] = __float2bfloat16(W[threadIdx.x * DDIM + blockIdx.x]);
}

// ---------------- pass 1: LDS-staged coarse binning (dense segment writes) ----------------
// record = src | (dst&511)<<16 | bin<<25 ; bin = dst>>9.
__global__ __launch_bounds__(256) void bin1_k(
    const int* __restrict__ s0, const int* __restrict__ d0,
    const int* __restrict__ s1, const int* __restrict__ d1,
    const int* __restrict__ s2, const int* __restrict__ d2,
    int* __restrict__ cs_shard,      // [NSHARD][3N]
    int* __restrict__ gcur,          // [3][NCPAD]
    unsigned* __restrict__ recs,     // [3][NCPAD][CCAP]
    int N, int E) {
    __shared__ unsigned stage[T1];           // 16 KB
    __shared__ int hcnt[NCPAD], hoff[NCPAD], lbase[NCPAD], lcur[NCPAD];
    const int t = threadIdx.x;
    const int rel = blockIdx.y;
    const int* s = (rel == 0) ? s0 : (rel == 1) ? s1 : s2;
    const int* d = (rel == 0) ? d0 : (rel == 1) ? d1 : d2;
    const int e0 = blockIdx.x * T1;
    const int n = min(T1, E - e0);
    int* csb = cs_shard + ((size_t)(blockIdx.x & (NSHARD - 1)) * 3 + rel) * N;

    if (t < NCPAD) { hcnt[t] = 0; lcur[t] = 0; }
    __syncthreads();

    // phase A: read edges into regs, LDS histogram + sharded deg_out atomics
    int ssr[T1 / 256], ddr[T1 / 256];
    #pragma unroll
    for (int k = 0; k < T1 / 256; ++k) {
        const int li = k * 256 + t;
        const bool v = li < n;
        ssr[k] = v ? s[e0 + li] : -1;
        ddr[k] = v ? d[e0 + li] : -1;
        if (v) {
            atomicAdd(&hcnt[ddr[k] >> 9], 1);
            atomicAdd(&csb[ssr[k]], 1);
        }
    }
    __syncthreads();

    // phase B: wave-scan the 128 bin counts (2/lane), reserve global segments
    if (t < 64) {
        const int a0 = hcnt[2 * t], a1 = hcnt[2 * t + 1];
        const int sum = a0 + a1;
        int incl = sum;
        #pragma unroll
        for (int off = 1; off < 64; off <<= 1) {
            const int u = __shfl_up(incl, off);
            if (t >= off) incl += u;
        }
        const int excl = incl - sum;
        hoff[2 * t] = excl;
        hoff[2 * t + 1] = excl + a0;
    }
    __syncthreads();
    if (t < NCPAD) lbase[t] = atomicAdd(&gcur[rel * NCPAD + t], hcnt[t]);
    __syncthreads();

    // phase C: counting-scatter records into LDS (grouped by bin)
    #pragma unroll
    for (int k = 0; k < T1 / 256; ++k) {
        if (ddr[k] >= 0) {
            const int b = ddr[k] >> 9;
            const int p = atomicAdd(&lcur[b], 1);
            stage[hoff[b] + p] = (unsigned)ssr[k] | ((unsigned)(ddr[k] & 511) << 16)
                                 | ((unsigned)b << 25);
        }
    }
    __syncthreads();

    // phase D: dense segment writes (mean 32 records = 128 B per bin segment)
    for (int i = t; i < n; i += 256) {
        const unsigned r = stage[i];
        const int b = (int)(r >> 25);
        const int pos = lbase[b] + (i - hoff[b]);
        if (pos < CCAP)
            recs[((size_t)rel * NCPAD + b) * CCAP + pos] = r & 0x1FFFFFFu;
    }
}

// ---------------- fold sharded deg_out ----------------
__global__ void reduce_cs_k(const int* __restrict__ cs_shard, int* __restrict__ cs, int n3) {
    const int i = blockIdx.x * blockDim.x + threadIdx.x;
    if (i >= n3) return;
    int v = 0;
    #pragma unroll
    for (int s = 0; s < NSHARD; ++s) v += cs_shard[(size_t)s * n3 + i];
    cs[i] = v;
}

// ---------------- pass 2: per-coarse-bin LDS counting sort by dst row ----------------
// One block per (rel, bin). In-place rewrite of the bin region (L2-resident, ~36 KB).
__global__ __launch_bounds__(256) void sort_k(
    unsigned* __restrict__ recs, const int* __restrict__ gcur,
    int* __restrict__ row_beg, int* __restrict__ row_cnt, int N, int ncb) {
    __shared__ unsigned stage[CCAP];     // 36 KB
    __shared__ int rc[512], ro[512], rcur[512];
    const int t = threadIdx.x;
    const int rel = blockIdx.x / ncb, bin = blockIdx.x % ncb;
    const size_t base = ((size_t)rel * NCPAD + bin) * CCAP;
    const int n = min(gcur[rel * NCPAD + bin], CCAP);

    for (int i = t; i < 512; i += 256) rc[i] = 0;
    __syncthreads();
    for (int i = t; i < n; i += 256) {
        const unsigned r = recs[base + i];
        stage[i] = r;
        atomicAdd(&rc[(r >> 16) & 511], 1);
    }
    __syncthreads();
    // wave-scan 512 counters (8/lane)
    if (t < 64) {
        int v[8], p[8], sum = 0;
        #pragma unroll
        for (int j = 0; j < 8; ++j) { v[j] = rc[t * 8 + j]; p[j] = sum; sum += v[j]; }
        int incl = sum;
        #pragma unroll
        for (int off = 1; off < 64; off <<= 1) {
            const int u = __shfl_up(incl, off);
            if (t >= off) incl += u;
        }
        const int excl = incl - sum;
        #pragma unroll
        for (int j = 0; j < 8; ++j) { ro[t * 8 + j] = excl + p[j]; rcur[t * 8 + j] = excl + p[j]; }
    }
    __syncthreads();
    // emit row_beg / row_cnt
    for (int i = t; i < 512; i += 256) {
        const int grow = bin * 512 + i;
        if (grow < N) {
            row_cnt[(size_t)rel * N + grow] = rc[i];
            row_beg[(size_t)rel * N + grow] = (int)(base + ro[i]);
        }
    }
    // scatter back sorted (writes confined to the 36 KB region -> L2-merged)
    for (int i = t; i < n; i += 256) {
        const unsigned r = stage[i];
        const int pos = atomicAdd(&rcur[(r >> 16) & 511], 1);
        recs[base + pos] = r & 0xffffu;
    }
}

// ---------------- dual-output GEMM: Y0 = bf16(s0(X@W0)), Y1 = bf16(s1(X@W1)) ----------------
__global__ __launch_bounds__(256) void gemm2_k(
    const float* __restrict__ X,
    const __hip_bfloat16* __restrict__ Wt0, const __hip_bfloat16* __restrict__ Wt1,
    const int* __restrict__ deg0, const int* __restrict__ deg1,
    __hip_bfloat16* __restrict__ Y0, __hip_bfloat16* __restrict__ Y1, int M) {
    const int lane = threadIdx.x & 63, wid = threadIdx.x >> 6;
    const int c = lane & 15, kb = lane >> 4;
    const int rA = blockIdx.x * 128 + wid * 32 + c;
    const int rB = rA + 16;
    const bool vA = rA < M, vB = rB < M;
    const int rAc = vA ? rA : (M - 1), rBc = vB ? rB : (M - 1);

    s8v xfA[8], xfB[8];
    const float* xA = X + (size_t)rAc * DDIM;
    const float* xB = X + (size_t)rBc * DDIM;
    #pragma unroll
    for (int ks = 0; ks < 8; ++ks) {
        const int k0 = ks * 32 + kb * 8;
        const f4v a0 = *reinterpret_cast<const f4v*>(xA + k0);
        const f4v a1 = *reinterpret_cast<const f4v*>(xA + k0 + 4);
        const f4v b0 = *reinterpret_cast<const f4v*>(xB + k0);
        const f4v b1 = *reinterpret_cast<const f4v*>(xB + k0 + 4);
        union { s8v v; unsigned short u[8]; } fa, fb;
        #pragma unroll
        for (int j = 0; j < 4; ++j) {
            fa.u[j] = f2bf(a0[j]); fa.u[4 + j] = f2bf(a1[j]);
            fb.u[j] = f2bf(b0[j]); fb.u[4 + j] = f2bf(b1[j]);
        }
        xfA[ks] = fa.v; xfB[ks] = fb.v;
    }

    const int dA0 = deg0[rAc], dB0 = deg0[rBc], dA1 = deg1[rAc], dB1 = deg1[rBc];
    const float s0A = rsqrtf((float)(dA0 < 1 ? 1 : dA0));
    const float s0B = rsqrtf((float)(dB0 < 1 ? 1 : dB0));
    const float s1A = rsqrtf((float)(dA1 < 1 ? 1 : dA1));
    const float s1B = rsqrtf((float)(dB1 < 1 ? 1 : dB1));

    #pragma unroll 2
    for (int nt = 0; nt < 16; ++nt) {
        const __hip_bfloat16* w0p = Wt0 + (size_t)(nt * 16 + c) * DDIM + kb * 8;
        const __hip_bfloat16* w1p = Wt1 + (size_t)(nt * 16 + c) * DDIM + kb * 8;
        s8v wf0[8], wf1[8];
        #pragma unroll
        for (int ks = 0; ks < 8; ++ks) {
            wf0[ks] = *reinterpret_cast<const s8v*>(w0p + ks * 32);
            wf1[ks] = *reinterpret_cast<const s8v*>(w1p + ks * 32);
        }
        f4v a00 = (f4v){0.f,0.f,0.f,0.f}, a01 = a00, a10 = a00, a11 = a00;
        #pragma unroll
        for (int ks = 0; ks < 8; ++ks) {
            a00 = __builtin_amdgcn_mfma_f32_16x16x32_bf16(wf0[ks], xfA[ks], a00, 0, 0, 0);
            a10 = __builtin_amdgcn_mfma_f32_16x16x32_bf16(wf0[ks], xfB[ks], a10, 0, 0, 0);
            a01 = __builtin_amdgcn_mfma_f32_16x16x32_bf16(wf1[ks], xfA[ks], a01, 0, 0, 0);
            a11 = __builtin_amdgcn_mfma_f32_16x16x32_bf16(wf1[ks], xfB[ks], a11, 0, 0, 0);
        }
        const int col = nt * 16 + kb * 4;
        if (vA) {
            uint2 o0, o1;
            o0.x = pack2(a00[0] * s0A, a00[1] * s0A); o0.y = pack2(a00[2] * s0A, a00[3] * s0A);
            o1.x = pack2(a01[0] * s1A, a01[1] * s1A); o1.y = pack2(a01[2] * s1A, a01[3] * s1A);
            *reinterpret_cast<uint2*>(Y0 + (size_t)rA * DDIM + col) = o0;
            *reinterpret_cast<uint2*>(Y1 + (size_t)rA * DDIM + col) = o1;
        }
        if (vB) {
            uint2 o0, o1;
            o0.x = pack2(a10[0] * s0B, a10[1] * s0B); o0.y = pack2(a10[2] * s0B, a10[3] * s0B);
            o1.x = pack2(a11[0] * s1B, a11[1] * s1B); o1.y = pack2(a11[2] * s1B, a11[3] * s1B);
            *reinterpret_cast<uint2*>(Y0 + (size_t)rB * DDIM + col) = o0;
            *reinterpret_cast<uint2*>(Y1 + (size_t)rB * DDIM + col) = o1;
        }
    }
}

// ---------------- single-output GEMM ----------------
__global__ __launch_bounds__(256) void gemm1_k(
    const float* __restrict__ X, const __hip_bfloat16* __restrict__ Wt0,
    const int* __restrict__ deg0, __hip_bfloat16* __restrict__ Y0, int M) {
    const int lane = threadIdx.x & 63, wid = threadIdx.x >> 6;
    const int c = lane & 15, kb = lane >> 4;
    const int rA = blockIdx.x * 128 + wid * 32 + c;
    const int rB = rA + 16;
    const bool vA = rA < M, vB = rB < M;
    const int rAc = vA ? rA : (M - 1), rBc = vB ? rB : (M - 1);

    s8v xfA[8], xfB[8];
    const float* xA = X + (size_t)rAc * DDIM;
    const float* xB = X + (size_t)rBc * DDIM;
    #pragma unroll
    for (int ks = 0; ks < 8; ++ks) {
        const int k0 = ks * 32 + kb * 8;
        const f4v a0 = *reinterpret_cast<const f4v*>(xA + k0);
        const f4v a1 = *reinterpret_cast<const f4v*>(xA + k0 + 4);
        const f4v b0 = *reinterpret_cast<const f4v*>(xB + k0);
        const f4v b1 = *reinterpret_cast<const f4v*>(xB + k0 + 4);
        union { s8v v; unsigned short u[8]; } fa, fb;
        #pragma unroll
        for (int j = 0; j < 4; ++j) {
            fa.u[j] = f2bf(a0[j]); fa.u[4 + j] = f2bf(a1[j]);
            fb.u[j] = f2bf(b0[j]); fb.u[4 + j] = f2bf(b1[j]);
        }
        xfA[ks] = fa.v; xfB[ks] = fb.v;
    }
    const int dA0 = deg0[rAc], dB0 = deg0[rBc];
    const float s0A = rsqrtf((float)(dA0 < 1 ? 1 : dA0));
    const float s0B = rsqrtf((float)(dB0 < 1 ? 1 : dB0));

    #pragma unroll 2
    for (int nt = 0; nt < 16; ++nt) {
        const __hip_bfloat16* w0p = Wt0 + (size_t)(nt * 16 + c) * DDIM + kb * 8;
        s8v wf0[8];
        #pragma unroll
        for (int ks = 0; ks < 8; ++ks) wf0[ks] = *reinterpret_cast<const s8v*>(w0p + ks * 32);
        f4v a00 = (f4v){0.f,0.f,0.f,0.f}, a10 = a00;
        #pragma unroll
        for (int ks = 0; ks < 8; ++ks) {
            a00 = __builtin_amdgcn_mfma_f32_16x16x32_bf16(wf0[ks], xfA[ks], a00, 0, 0, 0);
            a10 = __builtin_amdgcn_mfma_f32_16x16x32_bf16(wf0[ks], xfB[ks], a10, 0, 0, 0);
        }
        const int col = nt * 16 + kb * 4;
        if (vA) {
            uint2 o;
            o.x = pack2(a00[0] * s0A, a00[1] * s0A); o.y = pack2(a00[2] * s0A, a00[3] * s0A);
            *reinterpret_cast<uint2*>(Y0 + (size_t)rA * DDIM + col) = o;
        }
        if (vB) {
            uint2 o;
            o.x = pack2(a10[0] * s0B, a10[1] * s0B); o.y = pack2(a10[2] * s0B, a10[3] * s0B);
            *reinterpret_cast<uint2*>(Y0 + (size_t)rB * DDIM + col) = o;
        }
    }
}

// ---------------- gather helpers ----------------
__device__ __forceinline__ void addv(f4v& a, uint2 v) {
    a[0] += bf2f(v.x & 0xffffu);
    a[1] += bf2f(v.x >> 16);
    a[2] += bf2f(v.y & 0xffffu);
    a[3] += bf2f(v.y >> 16);
}

// lane-parallel record fetch (one coalesced load per 64 records), 4-wide MLP on Y rows
__device__ __forceinline__ f4v segsum(const unsigned* __restrict__ recs, int beg, int n,
                                      const __hip_bfloat16* __restrict__ Y, int lane) {
    f4v a = (f4v){0.f, 0.f, 0.f, 0.f};
    for (int j0 = 0; j0 < n; j0 += 64) {
        const int chunk = min(64, n - j0);
        unsigned rv = 0;
        if (lane < chunk) rv = recs[beg + j0 + lane];
        int t = 0;
        for (; t + 4 <= chunk; t += 4) {
            const int s0 = (int)(__shfl(rv, t)     & 0xffffu);
            const int s1 = (int)(__shfl(rv, t + 1) & 0xffffu);
            const int s2 = (int)(__shfl(rv, t + 2) & 0xffffu);
            const int s3 = (int)(__shfl(rv, t + 3) & 0xffffu);
            const uint2 v0 = reinterpret_cast<const uint2*>(Y + (size_t)s0 * DDIM)[lane];
            const uint2 v1 = reinterpret_cast<const uint2*>(Y + (size_t)s1 * DDIM)[lane];
            const uint2 v2 = reinterpret_cast<const uint2*>(Y + (size_t)s2 * DDIM)[lane];
            const uint2 v3 = reinterpret_cast<const uint2*>(Y + (size_t)s3 * DDIM)[lane];
            addv(a, v0); addv(a, v1); addv(a, v2); addv(a, v3);
        }
        for (; t < chunk; ++t) {
            const int s = (int)(__shfl(rv, t) & 0xffffu);
            addv(a, reinterpret_cast<const uint2*>(Y + (size_t)s * DDIM)[lane]);
        }
    }
    return a;
}

// ---------------- gather (+ optional 2nd relation) + LayerNorm + bias + ReLU ----------------
__global__ __launch_bounds__(256) void gather_ln_k(
    const unsigned* __restrict__ recs,
    const int* __restrict__ beg0, const int* __restrict__ cnt0,
    const __hip_bfloat16* __restrict__ Y0,
    const int* __restrict__ beg1, const int* __restrict__ cnt1,
    const __hip_bfloat16* __restrict__ Y1,          // beg1 == null -> single relation
    const float* __restrict__ gamma, const float* __restrict__ beta,
    const float* __restrict__ bias, float* __restrict__ out, int n_dst) {
    const int lane = threadIdx.x & 63, wid = threadIdx.x >> 6;
    const int row = blockIdx.x * 4 + wid;
    if (row >= n_dst) return;

    const int n0 = cnt0[row];
    f4v a = segsum(recs, beg0[row], n0, Y0, lane);
    a *= rsqrtf((float)(n0 < 1 ? 1 : n0));
    if (beg1 != nullptr) {
        const int n1 = cnt1[row];
        f4v a1 = segsum(recs, beg1[row], n1, Y1, lane);
        a += a1 * rsqrtf((float)(n1 < 1 ? 1 : n1));
    }

    float s1 = a[0] + a[1] + a[2] + a[3];
    float s2 = a[0]*a[0] + a[1]*a[1] + a[2]*a[2] + a[3]*a[3];
    #pragma unroll
    for (int off = 1; off < 64; off <<= 1) {
        s1 += __shfl_xor(s1, off);
        s2 += __shfl_xor(s2, off);
    }
    const float mu = s1 * (1.f / 256.f);
    float var = s2 * (1.f / 256.f) - mu * mu;
    var = fmaxf(var, 0.f);
    const float rs = rsqrtf(var + 1e-5f);

    const f4v g  = reinterpret_cast<const f4v*>(gamma)[lane];
    const f4v be = reinterpret_cast<const f4v*>(beta)[lane];
    const f4v bb = reinterpret_cast<const f4v*>(bias)[lane];
    f4v o;
    #pragma unroll
    for (int j = 0; j < 4; ++j) {
        float v = (a[j] - mu) * rs * g[j] + be[j] + bb[j];
        o[j] = fmaxf(v, 0.f);
    }
    reinterpret_cast<f4v*>(out + (size_t)row * DDIM)[lane] = o;
}

extern "C" void kernel_launch(void* const* d_in, const int* in_sizes, int n_in,
                              void* d_out, int out_size, void* d_ws, size_t ws_size,
                              hipStream_t stream) {
    const float* x_cell     = (const float*)d_in[0];
    const float* x_gene     = (const float*)d_in[1];
    const float* W_cg       = (const float*)d_in[2];
    const float* W_gc       = (const float*)d_in[3];
    const float* W_gg       = (const float*)d_in[4];
    const float* gamma_cell = (const float*)d_in[5];
    const float* beta_cell  = (const float*)d_in[6];
    const float* gamma_gene = (const float*)d_in[7];
    const float* beta_gene  = (const float*)d_in[8];
    const float* b_cell     = (const float*)d_in[9];
    const float* b_gene     = (const float*)d_in[10];
    const int* src_cg = (const int*)d_in[11];
    const int* dst_cg = (const int*)d_in[12];
    const int* src_gc = (const int*)d_in[13];
    const int* dst_gc = (const int*)d_in[14];
    const int* src_gg = (const int*)d_in[15];
    const int* dst_gg = (const int*)d_in[16];

    const int N = in_sizes[0] / DDIM;        // 50000
    const int E = in_sizes[11];              // 800000
    const int ncb = (N + 511) >> 9;          // 98 used coarse bins

    // ---- workspace layout (~47 MB) ----
    char* wsb = (char*)d_ws;
    size_t off = 0;
    __hip_bfloat16* Y_gc = (__hip_bfloat16*)(wsb + off); off += (size_t)N * DDIM * 2;           // 25.6 MB
    unsigned* recs = (unsigned*)(wsb + off);             off += (size_t)3 * NCPAD * CCAP * 4;   // 14.2 MB
    int* row_beg = (int*)(wsb + off);                    off += (size_t)3 * N * 4;              // 600 KB
    int* row_cnt = (int*)(wsb + off);                    off += (size_t)3 * N * 4;              // 600 KB
    int* cs      = (int*)(wsb + off);                    off += (size_t)3 * N * 4;              // 600 KB
    const size_t zeroOff = off;
    int* cs_shard = (int*)(wsb + off);                   off += (size_t)NSHARD * 3 * N * 4;     // 4.8 MB
    int* gcur     = (int*)(wsb + off);                   off += (size_t)3 * NCPAD * 4;          // 1.5 KB
    const size_t zeroBytes = off - zeroOff;
    __hip_bfloat16* Wt_gc = (__hip_bfloat16*)(wsb + off); off += (size_t)DDIM * DDIM * 2;
    __hip_bfloat16* Wt_cg = (__hip_bfloat16*)(wsb + off); off += (size_t)DDIM * DDIM * 2;
    __hip_bfloat16* Wt_gg = (__hip_bfloat16*)(wsb + off);

    int* cs_gc = cs, *cs_cg = cs + N, *cs_gg = cs + 2 * N;
    int* beg_gc = row_beg, *beg_cg = row_beg + N, *beg_gg = row_beg + 2 * N;
    int* cnt_gc = row_cnt, *cnt_cg = row_cnt + N, *cnt_gg = row_cnt + 2 * N;

    // Y_cg, Y_gg live in the d_out cell-half; consumed by the gene gather before
    // the cell gather overwrites that region with the final cell output.
    float* out_cell = (float*)d_out;
    float* out_gene = out_cell + (size_t)N * DDIM;
    __hip_bfloat16* Y_cg = (__hip_bfloat16*)d_out;
    __hip_bfloat16* Y_gg = Y_cg + (size_t)N * DDIM;

    const int binBlocks  = (E + T1 - 1) / T1;
    const int gemmBlocks = (N + 127) / 128;
    const int gatherBlocks = (N + 3) / 4;

    transpose3_k<<<dim3(DDIM, 3), DDIM, 0, stream>>>(W_gc, W_cg, W_gg, Wt_gc, Wt_cg, Wt_gg);
    hipMemsetAsync(wsb + zeroOff, 0, zeroBytes, stream);

    // relations: 0=gc, 1=cg, 2=gg
    bin1_k<<<dim3(binBlocks, 3), 256, 0, stream>>>(src_gc, dst_gc, src_cg, dst_cg,
                                                   src_gg, dst_gg, cs_shard, gcur, recs, N, E);
    reduce_cs_k<<<(3 * N + 255) / 256, 256, 0, stream>>>(cs_shard, cs, 3 * N);
    sort_k<<<3 * ncb, 256, 0, stream>>>(recs, gcur, row_beg, row_cnt, N, ncb);

    gemm2_k<<<gemmBlocks, 256, 0, stream>>>(x_gene, Wt_gc, Wt_gg, cs_gc, cs_gg,
                                            Y_gc, Y_gg, N);
    gemm1_k<<<gemmBlocks, 256, 0, stream>>>(x_cell, Wt_cg, cs_cg, Y_cg, N);

    // gene: cg + gg fused gather + LN
    gather_ln_k<<<gatherBlocks, 256, 0, stream>>>(recs, beg_cg, cnt_cg, Y_cg,
                                                  beg_gg, cnt_gg, Y_gg,
                                                  gamma_gene, beta_gene, b_gene, out_gene, N);
    // cell: gc gather + LN (overwrites Y_cg/Y_gg region)
    gather_ln_k<<<gatherBlocks, 256, 0, stream>>>(recs, beg_gc, cnt_gc, Y_gc,
                                                  nullptr, nullptr, nullptr,
                                                  gamma_cell, beta_cell, b_cell, out_cell, N);
}

// Round 9
// 420.057 us; speedup vs baseline: 9.4819x; 1.0029x over previous
//
#include <hip/hip_runtime.h>
#include <hip/hip_bf16.h>
#include <stdint.h>

#define DDIM 256
#define NSHARD 8          // shards for deg_out atomics
#define T1 4096           // edges per bin1 block
#define NCPAD 128         // padded coarse-bin count (dst>>9, 512 rows/bin)
#define CCAP 9216         // record capacity per (rel, coarse bin); mean 8192, +11 sigma

typedef short s8v __attribute__((ext_vector_type(8)));
typedef float f4v __attribute__((ext_vector_type(4)));

__device__ __forceinline__ float bf2f(unsigned u) { return __uint_as_float(u << 16); }
__device__ __forceinline__ unsigned short f2bf(float f) {
    __hip_bfloat16 h = __float2bfloat16(f);
    return *reinterpret_cast<unsigned short*>(&h);
}
__device__ __forceinline__ unsigned pack2(float a, float b) {
    return (unsigned)f2bf(a) | ((unsigned)f2bf(b) << 16);
}

// ---------------- fused W transpose + cast: T[n][k] = bf16(W[k][n]) ----------------
__global__ void transpose3_k(const float* __restrict__ W0, const float* __restrict__ W1,
                             const float* __restrict__ W2, __hip_bfloat16* __restrict__ T0,
                             __hip_bfloat16* __restrict__ T1v, __hip_bfloat16* __restrict__ T2) {
    const float* W = (blockIdx.y == 0) ? W0 : (blockIdx.y == 1) ? W1 : W2;
    __hip_bfloat16* T = (blockIdx.y == 0) ? T0 : (blockIdx.y == 1) ? T1v : T2;
    T[blockIdx.x * DDIM + threadIdx.x] = __float2bfloat16(W[threadIdx.x * DDIM + blockIdx.x]);
}

// ---------------- pass 1: LDS-staged coarse binning (dense segment writes) ----------------
// record = src | (dst&511)<<16 | bin<<25 ; bin = dst>>9.
__global__ __launch_bounds__(256) void bin1_k(
    const int* __restrict__ s0, const int* __restrict__ d0,
    const int* __restrict__ s1, const int* __restrict__ d1,
    const int* __restrict__ s2, const int* __restrict__ d2,
    int* __restrict__ cs_shard,      // [NSHARD][3N]
    int* __restrict__ gcur,          // [3][NCPAD]
    unsigned* __restrict__ recs,     // [3][NCPAD][CCAP]
    int N, int E) {
    __shared__ unsigned stage[T1];           // 16 KB
    __shared__ int hcnt[NCPAD], hoff[NCPAD], lbase[NCPAD], lcur[NCPAD];
    const int t = threadIdx.x;
    const int rel = blockIdx.y;
    const int* s = (rel == 0) ? s0 : (rel == 1) ? s1 : s2;
    const int* d = (rel == 0) ? d0 : (rel == 1) ? d1 : d2;
    const int e0 = blockIdx.x * T1;
    const int n = min(T1, E - e0);
    int* csb = cs_shard + ((size_t)(blockIdx.x & (NSHARD - 1)) * 3 + rel) * N;

    if (t < NCPAD) { hcnt[t] = 0; lcur[t] = 0; }
    __syncthreads();

    // phase A: read edges into regs, LDS histogram + sharded deg_out atomics
    int ssr[T1 / 256], ddr[T1 / 256];
    #pragma unroll
    for (int k = 0; k < T1 / 256; ++k) {
        const int li = k * 256 + t;
        const bool v = li < n;
        ssr[k] = v ? s[e0 + li] : -1;
        ddr[k] = v ? d[e0 + li] : -1;
        if (v) {
            atomicAdd(&hcnt[ddr[k] >> 9], 1);
            atomicAdd(&csb[ssr[k]], 1);
        }
    }
    __syncthreads();

    // phase B: wave-scan the 128 bin counts (2/lane), reserve global segments
    if (t < 64) {
        const int a0 = hcnt[2 * t], a1 = hcnt[2 * t + 1];
        const int sum = a0 + a1;
        int incl = sum;
        #pragma unroll
        for (int off = 1; off < 64; off <<= 1) {
            const int u = __shfl_up(incl, off);
            if (t >= off) incl += u;
        }
        const int excl = incl - sum;
        hoff[2 * t] = excl;
        hoff[2 * t + 1] = excl + a0;
    }
    __syncthreads();
    if (t < NCPAD) lbase[t] = atomicAdd(&gcur[rel * NCPAD + t], hcnt[t]);
    __syncthreads();

    // phase C: counting-scatter records into LDS (grouped by bin)
    #pragma unroll
    for (int k = 0; k < T1 / 256; ++k) {
        if (ddr[k] >= 0) {
            const int b = ddr[k] >> 9;
            const int p = atomicAdd(&lcur[b], 1);
            stage[hoff[b] + p] = (unsigned)ssr[k] | ((unsigned)(ddr[k] & 511) << 16)
                                 | ((unsigned)b << 25);
        }
    }
    __syncthreads();

    // phase D: dense segment writes (mean 32 records = 128 B per bin segment)
    for (int i = t; i < n; i += 256) {
        const unsigned r = stage[i];
        const int b = (int)(r >> 25);
        const int pos = lbase[b] + (i - hoff[b]);
        if (pos < CCAP)
            recs[((size_t)rel * NCPAD + b) * CCAP + pos] = r & 0x1FFFFFFu;
    }
}

// ---------------- fold sharded deg_out ----------------
__global__ void reduce_cs_k(const int* __restrict__ cs_shard, int* __restrict__ cs, int n3) {
    const int i = blockIdx.x * blockDim.x + threadIdx.x;
    if (i >= n3) return;
    int v = 0;
    #pragma unroll
    for (int s = 0; s < NSHARD; ++s) v += cs_shard[(size_t)s * n3 + i];
    cs[i] = v;
}

// ---------------- pass 2: per-coarse-bin LDS counting sort by dst row ----------------
__global__ __launch_bounds__(256) void sort_k(
    unsigned* __restrict__ recs, const int* __restrict__ gcur,
    int* __restrict__ row_beg, int* __restrict__ row_cnt, int N, int ncb) {
    __shared__ unsigned stage[CCAP];     // 36 KB
    __shared__ int rc[512], ro[512], rcur[512];
    const int t = threadIdx.x;
    const int rel = blockIdx.x / ncb, bin = blockIdx.x % ncb;
    const size_t base = ((size_t)rel * NCPAD + bin) * CCAP;
    const int n = min(gcur[rel * NCPAD + bin], CCAP);

    for (int i = t; i < 512; i += 256) rc[i] = 0;
    __syncthreads();
    for (int i = t; i < n; i += 256) {
        const unsigned r = recs[base + i];
        stage[i] = r;
        atomicAdd(&rc[(r >> 16) & 511], 1);
    }
    __syncthreads();
    // wave-scan 512 counters (8/lane)
    if (t < 64) {
        int v[8], p[8], sum = 0;
        #pragma unroll
        for (int j = 0; j < 8; ++j) { v[j] = rc[t * 8 + j]; p[j] = sum; sum += v[j]; }
        int incl = sum;
        #pragma unroll
        for (int off = 1; off < 64; off <<= 1) {
            const int u = __shfl_up(incl, off);
            if (t >= off) incl += u;
        }
        const int excl = incl - sum;
        #pragma unroll
        for (int j = 0; j < 8; ++j) { ro[t * 8 + j] = excl + p[j]; rcur[t * 8 + j] = excl + p[j]; }
    }
    __syncthreads();
    for (int i = t; i < 512; i += 256) {
        const int grow = bin * 512 + i;
        if (grow < N) {
            row_cnt[(size_t)rel * N + grow] = rc[i];
            row_beg[(size_t)rel * N + grow] = (int)(base + ro[i]);
        }
    }
    for (int i = t; i < n; i += 256) {
        const unsigned r = stage[i];
        const int pos = atomicAdd(&rcur[(r >> 16) & 511], 1);
        recs[base + pos] = r & 0xffffu;
    }
}

// ---------------- dual-output GEMM: Y0 = bf16(s0(X@W0)), Y1 = bf16(s1(X@W1)) ----------------
// launch_bounds(256,2): ~256 VGPR budget so xf/wf/acc all stay in registers and the
// 16 Wt loads per nt issue in parallel (previous 68-VGPR compile serialized them).
__global__ __launch_bounds__(256, 2) void gemm2_k(
    const float* __restrict__ X,
    const __hip_bfloat16* __restrict__ Wt0, const __hip_bfloat16* __restrict__ Wt1,
    const int* __restrict__ deg0, const int* __restrict__ deg1,
    __hip_bfloat16* __restrict__ Y0, __hip_bfloat16* __restrict__ Y1, int M) {
    const int lane = threadIdx.x & 63, wid = threadIdx.x >> 6;
    const int c = lane & 15, kb = lane >> 4;
    const int rA = blockIdx.x * 128 + wid * 32 + c;
    const int rB = rA + 16;
    const bool vA = rA < M, vB = rB < M;
    const int rAc = vA ? rA : (M - 1), rBc = vB ? rB : (M - 1);

    s8v xfA[8], xfB[8];
    const float* xA = X + (size_t)rAc * DDIM;
    const float* xB = X + (size_t)rBc * DDIM;
    #pragma unroll
    for (int ks = 0; ks < 8; ++ks) {
        const int k0 = ks * 32 + kb * 8;
        const f4v a0 = *reinterpret_cast<const f4v*>(xA + k0);
        const f4v a1 = *reinterpret_cast<const f4v*>(xA + k0 + 4);
        const f4v b0 = *reinterpret_cast<const f4v*>(xB + k0);
        const f4v b1 = *reinterpret_cast<const f4v*>(xB + k0 + 4);
        union { s8v v; unsigned short u[8]; } fa, fb;
        #pragma unroll
        for (int j = 0; j < 4; ++j) {
            fa.u[j] = f2bf(a0[j]); fa.u[4 + j] = f2bf(a1[j]);
            fb.u[j] = f2bf(b0[j]); fb.u[4 + j] = f2bf(b1[j]);
        }
        xfA[ks] = fa.v; xfB[ks] = fb.v;
    }

    const int dA0 = deg0[rAc], dB0 = deg0[rBc], dA1 = deg1[rAc], dB1 = deg1[rBc];
    const float s0A = rsqrtf((float)(dA0 < 1 ? 1 : dA0));
    const float s0B = rsqrtf((float)(dB0 < 1 ? 1 : dB0));
    const float s1A = rsqrtf((float)(dA1 < 1 ? 1 : dA1));
    const float s1B = rsqrtf((float)(dB1 < 1 ? 1 : dB1));

    #pragma unroll 2
    for (int nt = 0; nt < 16; ++nt) {
        const __hip_bfloat16* w0p = Wt0 + (size_t)(nt * 16 + c) * DDIM + kb * 8;
        const __hip_bfloat16* w1p = Wt1 + (size_t)(nt * 16 + c) * DDIM + kb * 8;
        s8v wf0[8], wf1[8];
        #pragma unroll
        for (int ks = 0; ks < 8; ++ks) {
            wf0[ks] = *reinterpret_cast<const s8v*>(w0p + ks * 32);
            wf1[ks] = *reinterpret_cast<const s8v*>(w1p + ks * 32);
        }
        f4v a00 = (f4v){0.f,0.f,0.f,0.f}, a01 = a00, a10 = a00, a11 = a00;
        #pragma unroll
        for (int ks = 0; ks < 8; ++ks) {
            a00 = __builtin_amdgcn_mfma_f32_16x16x32_bf16(wf0[ks], xfA[ks], a00, 0, 0, 0);
            a10 = __builtin_amdgcn_mfma_f32_16x16x32_bf16(wf0[ks], xfB[ks], a10, 0, 0, 0);
            a01 = __builtin_amdgcn_mfma_f32_16x16x32_bf16(wf1[ks], xfA[ks], a01, 0, 0, 0);
            a11 = __builtin_amdgcn_mfma_f32_16x16x32_bf16(wf1[ks], xfB[ks], a11, 0, 0, 0);
        }
        const int col = nt * 16 + kb * 4;
        if (vA) {
            uint2 o0, o1;
            o0.x = pack2(a00[0] * s0A, a00[1] * s0A); o0.y = pack2(a00[2] * s0A, a00[3] * s0A);
            o1.x = pack2(a01[0] * s1A, a01[1] * s1A); o1.y = pack2(a01[2] * s1A, a01[3] * s1A);
            *reinterpret_cast<uint2*>(Y0 + (size_t)rA * DDIM + col) = o0;
            *reinterpret_cast<uint2*>(Y1 + (size_t)rA * DDIM + col) = o1;
        }
        if (vB) {
            uint2 o0, o1;
            o0.x = pack2(a10[0] * s0B, a10[1] * s0B); o0.y = pack2(a10[2] * s0B, a10[3] * s0B);
            o1.x = pack2(a11[0] * s1B, a11[1] * s1B); o1.y = pack2(a11[2] * s1B, a11[3] * s1B);
            *reinterpret_cast<uint2*>(Y0 + (size_t)rB * DDIM + col) = o0;
            *reinterpret_cast<uint2*>(Y1 + (size_t)rB * DDIM + col) = o1;
        }
    }
}

// ---------------- single-output GEMM ----------------
__global__ __launch_bounds__(256, 2) void gemm1_k(
    const float* __restrict__ X, const __hip_bfloat16* __restrict__ Wt0,
    const int* __restrict__ deg0, __hip_bfloat16* __restrict__ Y0, int M) {
    const int lane = threadIdx.x & 63, wid = threadIdx.x >> 6;
    const int c = lane & 15, kb = lane >> 4;
    const int rA = blockIdx.x * 128 + wid * 32 + c;
    const int rB = rA + 16;
    const bool vA = rA < M, vB = rB < M;
    const int rAc = vA ? rA : (M - 1), rBc = vB ? rB : (M - 1);

    s8v xfA[8], xfB[8];
    const float* xA = X + (size_t)rAc * DDIM;
    const float* xB = X + (size_t)rBc * DDIM;
    #pragma unroll
    for (int ks = 0; ks < 8; ++ks) {
        const int k0 = ks * 32 + kb * 8;
        const f4v a0 = *reinterpret_cast<const f4v*>(xA + k0);
        const f4v a1 = *reinterpret_cast<const f4v*>(xA + k0 + 4);
        const f4v b0 = *reinterpret_cast<const f4v*>(xB + k0);
        const f4v b1 = *reinterpret_cast<const f4v*>(xB + k0 + 4);
        union { s8v v; unsigned short u[8]; } fa, fb;
        #pragma unroll
        for (int j = 0; j < 4; ++j) {
            fa.u[j] = f2bf(a0[j]); fa.u[4 + j] = f2bf(a1[j]);
            fb.u[j] = f2bf(b0[j]); fb.u[4 + j] = f2bf(b1[j]);
        }
        xfA[ks] = fa.v; xfB[ks] = fb.v;
    }
    const int dA0 = deg0[rAc], dB0 = deg0[rBc];
    const float s0A = rsqrtf((float)(dA0 < 1 ? 1 : dA0));
    const float s0B = rsqrtf((float)(dB0 < 1 ? 1 : dB0));

    #pragma unroll 2
    for (int nt = 0; nt < 16; ++nt) {
        const __hip_bfloat16* w0p = Wt0 + (size_t)(nt * 16 + c) * DDIM + kb * 8;
        s8v wf0[8];
        #pragma unroll
        for (int ks = 0; ks < 8; ++ks) wf0[ks] = *reinterpret_cast<const s8v*>(w0p + ks * 32);
        f4v a00 = (f4v){0.f,0.f,0.f,0.f}, a10 = a00;
        #pragma unroll
        for (int ks = 0; ks < 8; ++ks) {
            a00 = __builtin_amdgcn_mfma_f32_16x16x32_bf16(wf0[ks], xfA[ks], a00, 0, 0, 0);
            a10 = __builtin_amdgcn_mfma_f32_16x16x32_bf16(wf0[ks], xfB[ks], a10, 0, 0, 0);
        }
        const int col = nt * 16 + kb * 4;
        if (vA) {
            uint2 o;
            o.x = pack2(a00[0] * s0A, a00[1] * s0A); o.y = pack2(a00[2] * s0A, a00[3] * s0A);
            *reinterpret_cast<uint2*>(Y0 + (size_t)rA * DDIM + col) = o;
        }
        if (vB) {
            uint2 o;
            o.x = pack2(a10[0] * s0B, a10[1] * s0B); o.y = pack2(a10[2] * s0B, a10[3] * s0B);
            *reinterpret_cast<uint2*>(Y0 + (size_t)rB * DDIM + col) = o;
        }
    }
}

// ---------------- gather helpers ----------------
__device__ __forceinline__ void addv(f4v& a, uint2 v) {
    a[0] += bf2f(v.x & 0xffffu);
    a[1] += bf2f(v.x >> 16);
    a[2] += bf2f(v.y & 0xffffu);
    a[3] += bf2f(v.y >> 16);
}

// lane-parallel record fetch + 8-deep batched Y-row loads (needs >64 VGPR budget)
__device__ __forceinline__ f4v segsum(const unsigned* __restrict__ recs, int beg, int n,
                                      const __hip_bfloat16* __restrict__ Y, int lane) {
    f4v a = (f4v){0.f, 0.f, 0.f, 0.f};
    for (int j0 = 0; j0 < n; j0 += 64) {
        const int chunk = min(64, n - j0);
        unsigned rv = 0;
        if (lane < chunk) rv = recs[beg + j0 + lane];
        int t = 0;
        for (; t + 8 <= chunk; t += 8) {
            uint2 v[8];
            #pragma unroll
            for (int i = 0; i < 8; ++i) {
                const int s = (int)(__shfl(rv, t + i) & 0xffffu);
                v[i] = reinterpret_cast<const uint2*>(Y + (size_t)s * DDIM)[lane];
            }
            #pragma unroll
            for (int i = 0; i < 8; ++i) addv(a, v[i]);
        }
        if (t + 4 <= chunk) {
            uint2 v[4];
            #pragma unroll
            for (int i = 0; i < 4; ++i) {
                const int s = (int)(__shfl(rv, t + i) & 0xffffu);
                v[i] = reinterpret_cast<const uint2*>(Y + (size_t)s * DDIM)[lane];
            }
            #pragma unroll
            for (int i = 0; i < 4; ++i) addv(a, v[i]);
            t += 4;
        }
        for (; t < chunk; ++t) {
            const int s = (int)(__shfl(rv, t) & 0xffffu);
            addv(a, reinterpret_cast<const uint2*>(Y + (size_t)s * DDIM)[lane]);
        }
    }
    return a;
}

// ---------------- gather (+ optional 2nd relation) + LayerNorm + bias + ReLU ----------------
__global__ __launch_bounds__(256, 4) void gather_ln_k(
    const unsigned* __restrict__ recs,
    const int* __restrict__ beg0, const int* __restrict__ cnt0,
    const __hip_bfloat16* __restrict__ Y0,
    const int* __restrict__ beg1, const int* __restrict__ cnt1,
    const __hip_bfloat16* __restrict__ Y1,          // beg1 == null -> single relation
    const float* __restrict__ gamma, const float* __restrict__ beta,
    const float* __restrict__ bias, float* __restrict__ out, int n_dst) {
    const int lane = threadIdx.x & 63, wid = threadIdx.x >> 6;
    const int row = blockIdx.x * 4 + wid;
    if (row >= n_dst) return;

    const int n0 = cnt0[row];
    f4v a = segsum(recs, beg0[row], n0, Y0, lane);
    a *= rsqrtf((float)(n0 < 1 ? 1 : n0));
    if (beg1 != nullptr) {
        const int n1 = cnt1[row];
        f4v a1 = segsum(recs, beg1[row], n1, Y1, lane);
        a += a1 * rsqrtf((float)(n1 < 1 ? 1 : n1));
    }

    float s1 = a[0] + a[1] + a[2] + a[3];
    float s2 = a[0]*a[0] + a[1]*a[1] + a[2]*a[2] + a[3]*a[3];
    #pragma unroll
    for (int off = 1; off < 64; off <<= 1) {
        s1 += __shfl_xor(s1, off);
        s2 += __shfl_xor(s2, off);
    }
    const float mu = s1 * (1.f / 256.f);
    float var = s2 * (1.f / 256.f) - mu * mu;
    var = fmaxf(var, 0.f);
    const float rs = rsqrtf(var + 1e-5f);

    const f4v g  = reinterpret_cast<const f4v*>(gamma)[lane];
    const f4v be = reinterpret_cast<const f4v*>(beta)[lane];
    const f4v bb = reinterpret_cast<const f4v*>(bias)[lane];
    f4v o;
    #pragma unroll
    for (int j = 0; j < 4; ++j) {
        float v = (a[j] - mu) * rs * g[j] + be[j] + bb[j];
        o[j] = fmaxf(v, 0.f);
    }
    reinterpret_cast<f4v*>(out + (size_t)row * DDIM)[lane] = o;
}

extern "C" void kernel_launch(void* const* d_in, const int* in_sizes, int n_in,
                              void* d_out, int out_size, void* d_ws, size_t ws_size,
                              hipStream_t stream) {
    const float* x_cell     = (const float*)d_in[0];
    const float* x_gene     = (const float*)d_in[1];
    const float* W_cg       = (const float*)d_in[2];
    const float* W_gc       = (const float*)d_in[3];
    const float* W_gg       = (const float*)d_in[4];
    const float* gamma_cell = (const float*)d_in[5];
    const float* beta_cell  = (const float*)d_in[6];
    const float* gamma_gene = (const float*)d_in[7];
    const float* beta_gene  = (const float*)d_in[8];
    const float* b_cell     = (const float*)d_in[9];
    const float* b_gene     = (const float*)d_in[10];
    const int* src_cg = (const int*)d_in[11];
    const int* dst_cg = (const int*)d_in[12];
    const int* src_gc = (const int*)d_in[13];
    const int* dst_gc = (const int*)d_in[14];
    const int* src_gg = (const int*)d_in[15];
    const int* dst_gg = (const int*)d_in[16];

    const int N = in_sizes[0] / DDIM;        // 50000
    const int E = in_sizes[11];              // 800000
    const int ncb = (N + 511) >> 9;          // 98 used coarse bins

    // ---- workspace layout (~47 MB) ----
    char* wsb = (char*)d_ws;
    size_t off = 0;
    __hip_bfloat16* Y_gc = (__hip_bfloat16*)(wsb + off); off += (size_t)N * DDIM * 2;           // 25.6 MB
    unsigned* recs = (unsigned*)(wsb + off);             off += (size_t)3 * NCPAD * CCAP * 4;   // 14.2 MB
    int* row_beg = (int*)(wsb + off);                    off += (size_t)3 * N * 4;              // 600 KB
    int* row_cnt = (int*)(wsb + off);                    off += (size_t)3 * N * 4;              // 600 KB
    int* cs      = (int*)(wsb + off);                    off += (size_t)3 * N * 4;              // 600 KB
    const size_t zeroOff = off;
    int* cs_shard = (int*)(wsb + off);                   off += (size_t)NSHARD * 3 * N * 4;     // 4.8 MB
    int* gcur     = (int*)(wsb + off);                   off += (size_t)3 * NCPAD * 4;          // 1.5 KB
    const size_t zeroBytes = off - zeroOff;
    __hip_bfloat16* Wt_gc = (__hip_bfloat16*)(wsb + off); off += (size_t)DDIM * DDIM * 2;
    __hip_bfloat16* Wt_cg = (__hip_bfloat16*)(wsb + off); off += (size_t)DDIM * DDIM * 2;
    __hip_bfloat16* Wt_gg = (__hip_bfloat16*)(wsb + off);

    int* cs_gc = cs, *cs_cg = cs + N, *cs_gg = cs + 2 * N;
    int* beg_gc = row_beg, *beg_cg = row_beg + N, *beg_gg = row_beg + 2 * N;
    int* cnt_gc = row_cnt, *cnt_cg = row_cnt + N, *cnt_gg = row_cnt + 2 * N;

    // Y_cg, Y_gg live in the d_out cell-half; consumed by the gene gather before
    // the cell gather overwrites that region with the final cell output.
    float* out_cell = (float*)d_out;
    float* out_gene = out_cell + (size_t)N * DDIM;
    __hip_bfloat16* Y_cg = (__hip_bfloat16*)d_out;
    __hip_bfloat16* Y_gg = Y_cg + (size_t)N * DDIM;

    const int binBlocks  = (E + T1 - 1) / T1;
    const int gemmBlocks = (N + 127) / 128;
    const int gatherBlocks = (N + 3) / 4;

    transpose3_k<<<dim3(DDIM, 3), DDIM, 0, stream>>>(W_gc, W_cg, W_gg, Wt_gc, Wt_cg, Wt_gg);
    hipMemsetAsync(wsb + zeroOff, 0, zeroBytes, stream);

    // relations: 0=gc, 1=cg, 2=gg
    bin1_k<<<dim3(binBlocks, 3), 256, 0, stream>>>(src_gc, dst_gc, src_cg, dst_cg,
                                                   src_gg, dst_gg, cs_shard, gcur, recs, N, E);
    reduce_cs_k<<<(3 * N + 255) / 256, 256, 0, stream>>>(cs_shard, cs, 3 * N);
    sort_k<<<3 * ncb, 256, 0, stream>>>(recs, gcur, row_beg, row_cnt, N, ncb);

    gemm2_k<<<gemmBlocks, 256, 0, stream>>>(x_gene, Wt_gc, Wt_gg, cs_gc, cs_gg,
                                            Y_gc, Y_gg, N);
    gemm1_k<<<gemmBlocks, 256, 0, stream>>>(x_cell, Wt_cg, cs_cg, Y_cg, N);

    // gene: cg + gg fused gather + LN
    gather_ln_k<<<gatherBlocks, 256, 0, stream>>>(recs, beg_cg, cnt_cg, Y_cg,
                                                  beg_gg, cnt_gg, Y_gg,
                                                  gamma_gene, beta_gene, b_gene, out_gene, N);
    // cell: gc gather + LN (overwrites Y_cg/Y_gg region)
    gather_ln_k<<<gatherBlocks, 256, 0, stream>>>(recs, beg_gc, cnt_gc, Y_gc,
                                                  nullptr, nullptr, nullptr,
                                                  gamma_cell, beta_cell, b_cell, out_cell, N);
}